// Round 18
// baseline (1484.369 us; speedup 1.0000x reference)
//
#include <hip/hip_runtime.h>
#include <hip/hip_bf16.h>
#include <math.h>
#include <float.h>

#define B_ 8
#define N_ 4096
#define M_ (B_*N_)
#define KNN 10

typedef unsigned long long ull;
typedef __attribute__((ext_vector_type(8))) short s16x8;
typedef __attribute__((ext_vector_type(4))) float f32x4;

__device__ __forceinline__ float mishf(float x){
  float sp = (x > 20.f) ? x : __logf(1.f + __expf(x));
  float e2 = __expf(-2.f*sp);
  float th = (1.f - e2) / (1.f + e2);
  return x * th;
}

__device__ __forceinline__ ull shfl_xor_u64(ull v, int mask){
  unsigned lo = (unsigned)v, hi = (unsigned)(v >> 32);
  lo = (unsigned)__shfl_xor((int)lo, mask);
  hi = (unsigned)__shfl_xor((int)hi, mask);
  return ((ull)hi << 32) | lo;
}
__device__ __forceinline__ ull shfl_u64(ull v, int src){
  unsigned lo = (unsigned)v, hi = (unsigned)(v >> 32);
  lo = (unsigned)__shfl((int)lo, src);
  hi = (unsigned)__shfl((int)hi, src);
  return ((ull)hi << 32) | lo;
}
__device__ __forceinline__ int mbcnt_lt(ull mask){
  return __builtin_amdgcn_mbcnt_hi((unsigned)(mask>>32),
         __builtin_amdgcn_mbcnt_lo((unsigned)mask, 0));
}
__device__ __forceinline__ unsigned mono_u32(float f){
  unsigned u = __float_as_uint(f);
  return u ^ ((unsigned)((int)u >> 31) | 0x80000000u);
}
__device__ __forceinline__ float unmono(unsigned vk){
  unsigned u = (vk & 0x80000000u) ? (vk ^ 0x80000000u) : ~vk;
  return __uint_as_float(u);
}
// async global->LDS, 16B per lane; lds dest is wave-uniform base + lane*16
__device__ __forceinline__ void gload_lds16(const void* g, void* l){
  __builtin_amdgcn_global_load_lds(
      (const __attribute__((address_space(1))) unsigned int*)g,
      (__attribute__((address_space(3))) unsigned int*)l, 16, 0, 0);
}

// ---------------- transpose x (B,3,N) -> xp (B*N,3) + xp4 {x,y,z,-xx/2} ------
__global__ __launch_bounds__(256) void k_transpose_x(const float* __restrict__ x,
                                                     float* __restrict__ xp,
                                                     float4* __restrict__ xp4){
  int n = blockIdx.x*256 + threadIdx.x;
  if (n >= M_) return;
  int b = n >> 12, i = n & (N_-1);
  const float* xb = x + (size_t)b*3*N_;
  float v0 = xb[i], v1 = xb[N_+i], v2 = xb[2*N_+i];
  float* o = xp + (size_t)n*3;
  o[0]=v0; o[1]=v1; o[2]=v2;
  float s = fmaf(v0,v0,0.f); s = fmaf(v1,v1,s); s = fmaf(v2,v2,s);
  xp4[n] = make_float4(v0, v1, v2, -0.5f*s);
}

// ---------------- fused: xx (exact k_xx<64> fmaf order) + bf16 hi/lo split ----
__global__ __launch_bounds__(256) void k_cvtxx(const float* __restrict__ X,
                                               ushort* __restrict__ Xhi,
                                               ushort* __restrict__ Xlo,
                                               float* __restrict__ xx){
  int n = blockIdx.x*256 + threadIdx.x;
  if (n >= M_) return;
  const float* r = X + (size_t)n*64;
  ushort* oh = Xhi + (size_t)n*64;
  ushort* ol = Xlo + (size_t)n*64;
  float s = 0.f;
#pragma unroll
  for (int g=0; g<8; ++g){
    float4 v0 = *(const float4*)(r + g*8);
    float4 v1 = *(const float4*)(r + g*8 + 4);
    float vv[8] = {v0.x,v0.y,v0.z,v0.w,v1.x,v1.y,v1.z,v1.w};
    unsigned hw[8], lw[8];
#pragma unroll
    for (int e=0;e<8;e++){
      float v = vv[e];
      s = fmaf(v,v,s);                       // c ascending: identical to k_xx<64>
      __hip_bfloat16 hb = __float2bfloat16(v);
      float hf = __bfloat162float(hb);
      __hip_bfloat16 lb = __float2bfloat16(v-hf);
      hw[e] = *(ushort*)&hb; lw[e] = *(ushort*)&lb;
    }
    uint4 hp, lp;
    hp.x = hw[0]|(hw[1]<<16); hp.y = hw[2]|(hw[3]<<16);
    hp.z = hw[4]|(hw[5]<<16); hp.w = hw[6]|(hw[7]<<16);
    lp.x = lw[0]|(lw[1]<<16); lp.y = lw[2]|(lw[3]<<16);
    lp.z = lw[4]|(lw[5]<<16); lp.w = lw[6]|(lw[7]<<16);
    *(uint4*)(oh + g*8) = hp;
    *(uint4*)(ol + g*8) = lp;
  }
  xx[n] = s;
}

// ---------------- C=3 kNN: per-thread-row streaming scan, 8 j-pieces --------
__global__ __launch_bounds__(256) void k_knn3s(const float4* __restrict__ xp4,
                                               ull* __restrict__ part){
  const int bid   = blockIdx.x;          // 8 batches x 16 rowgroups x 8 pieces
  const int piece = bid & 7;
  const int rg    = (bid >> 3) & 15;
  const int b     = bid >> 7;
  const int t     = threadIdx.x;
  const int row   = rg*256 + t;
  const float4 xi = xp4[(size_t)b*N_ + row];
  const float4* xj = xp4 + (size_t)b*N_ + piece*512;
  const int jbase = piece*512;

  ull kq[KNN];
#pragma unroll
  for (int q=0;q<KNN;q++) kq[q] = 0x007FFFFF00000000ull;   // packed -inf sentinel
  float T = -INFINITY;

  for (int jc=0; jc<512; jc+=8){
    float4 c[8];
#pragma unroll
    for (int u=0;u<8;u++) c[u] = xj[jc+u];
#pragma unroll
    for (int u=0;u<8;u++){
      float a = fmaf(xi.x, c[u].x, 0.f);
      a = fmaf(xi.y, c[u].y, a);
      a = fmaf(xi.z, c[u].z, a);
      float v = a + c[u].w;
      if (v > T){
        unsigned jinv = 4095u - (unsigned)(jbase + jc + u);
        ull ck = ((ull)mono_u32(v)<<32) | jinv;
#pragma unroll
        for (int q=0;q<KNN;q++){
          ull hi = ck > kq[q] ? ck : kq[q];
          ull lo = ck > kq[q] ? kq[q] : ck;
          kq[q] = hi; ck = lo;
        }
        T = unmono((unsigned)(kq[KNN-1] >> 32));
      }
    }
  }

  ull* o = part + ((size_t)(b*N_ + row)*8 + piece)*KNN;
#pragma unroll
  for (int q=0;q<KNN;q++) o[q] = kq[q];
}

// ---------------- merge eight sorted-10 key lists per row -> idx ----------------
__global__ __launch_bounds__(256) void k_knnmerge8(const ull* __restrict__ part,
                                                   int* __restrict__ idxout){
  int row = blockIdx.x*256 + threadIdx.x;
  if (row >= M_) return;
  const ull* p = part + (size_t)row*8*KNN;
  unsigned P = 0;
  int* o = idxout + (size_t)row*KNN;
  for (int s=0;s<KNN;s++){
    ull best = 0; int bl = 0;
#pragma unroll
    for (int l=0;l<8;l++){
      unsigned pl = (P >> (4*l)) & 15u;
      ull k = p[l*KNN + pl];
      if (k > best){ best = k; bl = l; }
    }
    P += 1u << (4*bl);
    o[s] = (int)(4095u - ((unsigned)best & 4095u));
  }
}

// ---------------- MFMA kNN (C=64, split-bf16 exact gram) -- R13 config -------
// Occupancy ladder FULLY explored (R7-R16): any min-waves>=3 cap spills;
// smaller LDS / 512-thr blocks don't raise residency. 385us = structural floor.
__global__ __launch_bounds__(256,2) void k_knn64m(const ushort* __restrict__ Xhi,
                                                  const ushort* __restrict__ Xlo,
                                                  const float* __restrict__ xx,
                                                  int* __restrict__ idxout){
  constexpr int JT  = 128;
  constexpr int NT  = N_/JT;
  constexpr int CAP = 320;
  __shared__ ushort XJhi[2][JT*64];   // content: LDS[r][c] = src[r][c ^ (r&7)] (16B chunks)
  __shared__ ushort XJlo[2][JT*64];
  __shared__ float  halfxx[2][JT];
  __shared__ ull    buf[4][CAP];

  const int t    = threadIdx.x;
  const int w    = t >> 6;
  const int lane = t & 63;
  const int b    = blockIdx.x & 7;          // XCD-swizzle: batch per XCD
  const int i0   = (blockIdx.x >> 3) * 64;
  const size_t rowbase = (size_t)b*N_;
  const float* xxb = xx + rowbase;

  const int arow = i0 + w*16 + (lane & 15);
  const ushort* Ah = Xhi + (rowbase + arow)*64;
  const ushort* Al = Xlo + (rowbase + arow)*64;
  const int ko = (lane >> 4)*8;
  s16x8 aH0 = *(const s16x8*)(Ah + ko);
  s16x8 aH1 = *(const s16x8*)(Ah + 32 + ko);
  s16x8 aL0 = *(const s16x8*)(Al + ko);
  s16x8 aL1 = *(const s16x8*)(Al + 32 + ko);

  ull kq[KNN];
#pragma unroll
  for (int q=0;q<KNN;q++) kq[q]=0ull;
  float Treg = -INFINITY;

  const int lr = lane >> 3;
  const int sc = (lane & 7) ^ lr;

  {
#pragma unroll
    for (int seg=0; seg<4; ++seg){
      const int row0 = w*32 + seg*8;
      gload_lds16(Xhi + (rowbase + row0 + lr)*64 + sc*8, &XJhi[0][row0*64]);
      gload_lds16(Xlo + (rowbase + row0 + lr)*64 + sc*8, &XJlo[0][row0*64]);
    }
    if (t < JT) halfxx[0][t] = 0.5f*xxb[t];
  }
  __syncthreads();

  for (int jt = 0; jt < NT; ++jt){
    const int cur = jt & 1;
    const int j0 = jt*JT;

    float hnext = 0.f;
    if (jt < NT-1){
      const size_t nb0 = rowbase + j0 + JT;
#pragma unroll
      for (int seg=0; seg<4; ++seg){
        const int row0 = w*32 + seg*8;
        gload_lds16(Xhi + (nb0 + row0 + lr)*64 + sc*8, &XJhi[cur^1][row0*64]);
        gload_lds16(Xlo + (nb0 + row0 + lr)*64 + sc*8, &XJlo[cur^1][row0*64]);
      }
      if (t < JT) hnext = 0.5f*xxb[j0 + JT + t];
    }

    f32x4 acc[8];
#pragma unroll
    for (int cb=0;cb<8;cb++) acc[cb] = (f32x4){0.f,0.f,0.f,0.f};

#pragma unroll
    for (int cb=0;cb<8;cb++){
      const int brow = cb*16 + (lane & 15);
      const unsigned sw = ((unsigned)(brow & 7)) << 4;
      const char* ph = (const char*)&XJhi[cur][0] + brow*128;
      const char* pl = (const char*)&XJlo[cur][0] + brow*128;
      const int kb0 = (int)((unsigned)((lane>>4)<<4) ^ sw);
      const int kb1 = (int)((unsigned)(64 | ((lane>>4)<<4)) ^ sw);
      s16x8 bh0 = *(const s16x8*)(ph + kb0);
      s16x8 bl0 = *(const s16x8*)(pl + kb0);
      s16x8 bh1 = *(const s16x8*)(ph + kb1);
      s16x8 bl1 = *(const s16x8*)(pl + kb1);
      f32x4 a = acc[cb];
      a = __builtin_amdgcn_mfma_f32_16x16x32_bf16(aH0, bh0, a, 0,0,0);
      a = __builtin_amdgcn_mfma_f32_16x16x32_bf16(aH0, bl0, a, 0,0,0);
      a = __builtin_amdgcn_mfma_f32_16x16x32_bf16(aL0, bh0, a, 0,0,0);
      a = __builtin_amdgcn_mfma_f32_16x16x32_bf16(aL0, bl0, a, 0,0,0);
      a = __builtin_amdgcn_mfma_f32_16x16x32_bf16(aH1, bh1, a, 0,0,0);
      a = __builtin_amdgcn_mfma_f32_16x16x32_bf16(aH1, bl1, a, 0,0,0);
      a = __builtin_amdgcn_mfma_f32_16x16x32_bf16(aL1, bh1, a, 0,0,0);
      a = __builtin_amdgcn_mfma_f32_16x16x32_bf16(aL1, bl1, a, 0,0,0);
      acc[cb] = a;
    }

    float hx[8];
#pragma unroll
    for (int cb=0;cb<8;cb++) hx[cb] = halfxx[cur][cb*16 + (lane & 15)];

    if (jt < NT-1 && t < JT) halfxx[cur^1][t] = hnext;

    if (jt == 0){
#pragma unroll
      for (int reg=0;reg<4;reg++){
        const unsigned rl = (unsigned)((lane>>4)*4 + reg);
        ull k8[8];
#pragma unroll
        for (int cb=0;cb<8;cb++){
          float v = acc[cb][reg] - hx[cb];
          unsigned jinv = 4095u - (unsigned)(cb*16 + (lane & 15));
          k8[cb] = ((ull)mono_u32(v)<<32) | ((ull)jinv<<4) | rl;
        }
#pragma unroll
        for (int q=0;q<KNN;q++){
          ull m = k8[0];
#pragma unroll
          for (int s=1;s<8;s++) m = m > k8[s] ? m : k8[s];
          ull v1 = shfl_xor_u64(m,1); m = m>v1?m:v1;
          ull v2 = shfl_xor_u64(m,2); m = m>v2?m:v2;
          ull v4 = shfl_xor_u64(m,4); m = m>v4?m:v4;
          ull v8 = shfl_xor_u64(m,8); m = m>v8?m:v8;
          ull mv = shfl_u64(m, (lane>>2)<<4);
          if (lane < 16 && (lane&3)==reg) kq[q] = mv;
#pragma unroll
          for (int s=0;s<8;s++) k8[s] = (k8[s]==m) ? 0ull : k8[s];
        }
      }
      Treg = unmono((unsigned)(kq[KNN-1] >> 32));
    } else {
      float Tf[4];
#pragma unroll
      for (int reg=0;reg<4;reg++) Tf[reg] = __shfl(Treg, (lane>>4)*4 + reg);
      int cnt = 0;
#pragma unroll
      for (int cb=0;cb<8;cb++){
#pragma unroll
        for (int reg=0;reg<4;reg++){
          float v = acc[cb][reg] - hx[cb];
          bool pass = v >= Tf[reg];
          ull mask = __ballot(pass);
          if (mask){
            if (pass){
              int slot = cnt + mbcnt_lt(mask);
              unsigned jinv = 4095u - (unsigned)(j0 + cb*16 + (lane & 15));
              ull key = ((ull)mono_u32(v)<<32) | ((ull)jinv<<4)
                        | (unsigned)((lane>>4)*4 + reg);
              if (slot < CAP) buf[w][slot] = key;
            }
            cnt += __popcll(mask);
          }
        }
      }
      if (cnt){
        int nb = cnt < CAP ? cnt : CAP;
        int pad = (4 - (nb & 3)) & 3;
        if (lane < pad && nb + lane < CAP) buf[w][nb + lane] = 0ull;
        int nb4 = nb + pad; if (nb4 > CAP) nb4 = CAP;
        for (int e=0;e<nb4;e+=4){
          ull c0=buf[w][e+0], c1=buf[w][e+1], c2=buf[w][e+2], c3=buf[w][e+3];
#pragma unroll
          for (int u=0;u<4;u++){
            ull k64 = (u==0)?c0:(u==1)?c1:(u==2)?c2:c3;
            if ((int)(k64 & 15ull) == lane && k64 > kq[KNN-1]){
              ull ck = k64;
#pragma unroll
              for (int q=0;q<KNN;q++){
                ull hi = ck > kq[q] ? ck : kq[q];
                ull lo = ck > kq[q] ? kq[q] : ck;
                kq[q] = hi; ck = lo;
              }
            }
          }
        }
        Treg = unmono((unsigned)(kq[KNN-1] >> 32));
      }
    }
    __syncthreads();
  }

  if (lane < 16){
    int* o = idxout + ((size_t)b*N_ + i0 + w*16 + lane)*KNN;
#pragma unroll
    for (int q=0;q<KNN;q++) o[q] = (int)(4095u - (unsigned)((kq[q]>>4) & 4095ull));
  }
}

// ---------------- generic GEMM: Y(M x Pfull) = act(s*(X1@Wa + X2@Wb)+b) ----------
template<int PT>
__global__ __launch_bounds__(256) void k_gemm(
    const float* __restrict__ X1, int C1,
    const float* __restrict__ X2, int C2,
    const float* __restrict__ W, int hmask, int hshift, int wstride, int hoff,
    const float* __restrict__ g, const float* __restrict__ bb, int act,
    float* __restrict__ Y, int Pfull)
{
  constexpr int CPT = PT/16;
  constexpr int WLS = PT + 4;
  __shared__ float Xt[32*68];
  __shared__ float Wt[32*WLS];
  const int t  = threadIdx.x;
  const int r0 = blockIdx.x*64;
  const int p0 = blockIdx.y*PT;
  const int cg = t & 15, rg = t >> 4;
  const int C = C1 + C2;
  const int nkt = (C + 31) >> 5;

  float acc[4][CPT];
#pragma unroll
  for (int a=0;a<4;a++)
#pragma unroll
    for (int c=0;c<CPT;c++) acc[a][c]=0.f;

  for (int kt = 0; kt < nkt; ++kt){
    const int k0 = kt*32;
#pragma unroll
    for (int e = t; e < 64*32; e += 256){
      int kk = e & 31, r = e >> 5;
      int gk = k0 + kk;
      float v = 0.f;
      if (gk < C1) v = X1[(size_t)(r0+r)*C1 + gk];
      else if (gk < C) v = X2[(size_t)(r0+r)*C2 + (gk - C1)];
      Xt[kk*68 + r] = v;
    }
#pragma unroll
    for (int e = t; e < PT*32; e += 256){
      int kk = e & 31, p = e >> 5;
      int gp = p0 + p;
      int wrow = (gp & hmask)*wstride + (gp >> hshift)*hoff;
      int gk = k0 + kk;
      Wt[kk*WLS + p] = (gk < C) ? W[(size_t)wrow + gk] : 0.f;
    }
    __syncthreads();
#pragma unroll
    for (int kk=0;kk<32;kk++){
      float4 xv = *(const float4*)&Xt[kk*68 + rg*4];
      float xr[4] = {xv.x, xv.y, xv.z, xv.w};
      float wv[CPT];
#pragma unroll
      for (int c4=0;c4<CPT/4;c4++){
        float4 w4 = *(const float4*)&Wt[kk*WLS + cg*CPT + c4*4];
        wv[c4*4+0]=w4.x; wv[c4*4+1]=w4.y; wv[c4*4+2]=w4.z; wv[c4*4+3]=w4.w;
      }
#pragma unroll
      for (int rr=0;rr<4;rr++)
#pragma unroll
        for (int cc=0;cc<CPT;cc++)
          acc[rr][cc] = fmaf(xr[rr], wv[cc], acc[rr][cc]);
    }
    __syncthreads();
  }

  const float srs = rsqrtf(1.f + 1e-5f);
  float sv[CPT], bvv[CPT];
#pragma unroll
  for (int cc=0;cc<CPT;cc++){
    int gp = p0 + cg*CPT + cc;
    if (g){ sv[cc] = g[gp]*srs; bvv[cc] = bb[gp]; } else { sv[cc]=1.f; bvv[cc]=0.f; }
  }
#pragma unroll
  for (int rr=0;rr<4;rr++){
    size_t row = r0 + rg*4 + rr;
    float* yr = Y + row*(size_t)Pfull + p0 + cg*CPT;
#pragma unroll
    for (int c4=0;c4<CPT/4;c4++){
      float y0 = sv[c4*4+0]*acc[rr][c4*4+0] + bvv[c4*4+0];
      float y1 = sv[c4*4+1]*acc[rr][c4*4+1] + bvv[c4*4+1];
      float y2 = sv[c4*4+2]*acc[rr][c4*4+2] + bvv[c4*4+2];
      float y3 = sv[c4*4+3]*acc[rr][c4*4+3] + bvv[c4*4+3];
      if (act){ y0=mishf(y0); y1=mishf(y1); y2=mishf(y2); y3=mishf(y3); }
      *(float4*)&yr[c4*4] = make_float4(y0,y1,y2,y3);
    }
  }
}

// ---------------- fused MLP W4+W5: x3 -> h4(LDS) -> cat(h4,x3) -> h5 ----------
// Row-local 1x1 convs: h4 never leaves LDS. fmaf chains identical to k_gemm<128>.
__global__ __launch_bounds__(256) void k_mlp45(
    const float* __restrict__ x3g,
    const float* __restrict__ W4, const float* __restrict__ g4, const float* __restrict__ b4,
    const float* __restrict__ W5, const float* __restrict__ g5, const float* __restrict__ b5,
    float* __restrict__ h5)
{
  __shared__ float Xt[32*68];
  __shared__ float Wt[32*132];
  __shared__ float h4t[64*132];          // row-major [row][col], stride 132
  const int t  = threadIdx.x;
  const int r0 = blockIdx.x*64;
  const int cg = t & 15, rg = t >> 4;
  const float srs = rsqrtf(1.f + 1e-5f);

  // ---- stage A: W4 (C=128 from x3), P=128 ----
  {
    float acc[4][8];
#pragma unroll
    for (int a=0;a<4;a++)
#pragma unroll
      for (int c=0;c<8;c++) acc[a][c]=0.f;
    for (int kt = 0; kt < 4; ++kt){
      const int k0 = kt*32;
#pragma unroll
      for (int e = t; e < 64*32; e += 256){
        int kk = e & 31, r = e >> 5;
        Xt[kk*68 + r] = x3g[(size_t)(r0+r)*128 + k0 + kk];
      }
#pragma unroll
      for (int e = t; e < 128*32; e += 256){
        int kk = e & 31, p = e >> 5;
        Wt[kk*132 + p] = W4[(size_t)p*128 + k0 + kk];
      }
      __syncthreads();
#pragma unroll
      for (int kk=0;kk<32;kk++){
        float4 xv = *(const float4*)&Xt[kk*68 + rg*4];
        float xr[4] = {xv.x, xv.y, xv.z, xv.w};
        float wv[8];
#pragma unroll
        for (int c4=0;c4<2;c4++){
          float4 w4v = *(const float4*)&Wt[kk*132 + cg*8 + c4*4];
          wv[c4*4+0]=w4v.x; wv[c4*4+1]=w4v.y; wv[c4*4+2]=w4v.z; wv[c4*4+3]=w4v.w;
        }
#pragma unroll
        for (int rr=0;rr<4;rr++)
#pragma unroll
          for (int cc=0;cc<8;cc++)
            acc[rr][cc] = fmaf(xr[rr], wv[cc], acc[rr][cc]);
      }
      __syncthreads();
    }
    float sv[8], bvv[8];
#pragma unroll
    for (int cc=0;cc<8;cc++){
      int gp = cg*8 + cc;
      sv[cc] = g4[gp]*srs; bvv[cc] = b4[gp];
    }
#pragma unroll
    for (int rr=0;rr<4;rr++){
      int row = rg*4 + rr;
#pragma unroll
      for (int cc=0;cc<8;cc++){
        float y = sv[cc]*acc[rr][cc] + bvv[cc];
        h4t[row*132 + cg*8 + cc] = mishf(y);
      }
    }
  }
  __syncthreads();

  // ---- stage B: W5 (C=256 = cat(h4 LDS, x3 global)), P=128 ----
  {
    float acc[4][8];
#pragma unroll
    for (int a=0;a<4;a++)
#pragma unroll
      for (int c=0;c<8;c++) acc[a][c]=0.f;
    for (int kt = 0; kt < 8; ++kt){
      const int k0 = kt*32;
#pragma unroll
      for (int e = t; e < 64*32; e += 256){
        int kk = e & 31, r = e >> 5;
        int gk = k0 + kk;
        float v = (gk < 128) ? h4t[r*132 + gk]
                             : x3g[(size_t)(r0+r)*128 + (gk - 128)];
        Xt[kk*68 + r] = v;
      }
#pragma unroll
      for (int e = t; e < 128*32; e += 256){
        int kk = e & 31, p = e >> 5;
        Wt[kk*132 + p] = W5[(size_t)p*256 + k0 + kk];
      }
      __syncthreads();
#pragma unroll
      for (int kk=0;kk<32;kk++){
        float4 xv = *(const float4*)&Xt[kk*68 + rg*4];
        float xr[4] = {xv.x, xv.y, xv.z, xv.w};
        float wv[8];
#pragma unroll
        for (int c4=0;c4<2;c4++){
          float4 w4v = *(const float4*)&Wt[kk*132 + cg*8 + c4*4];
          wv[c4*4+0]=w4v.x; wv[c4*4+1]=w4v.y; wv[c4*4+2]=w4v.z; wv[c4*4+3]=w4v.w;
        }
#pragma unroll
        for (int rr=0;rr<4;rr++)
#pragma unroll
          for (int cc=0;cc<8;cc++)
            acc[rr][cc] = fmaf(xr[rr], wv[cc], acc[rr][cc]);
      }
      __syncthreads();
    }
    float sv[8], bvv[8];
#pragma unroll
    for (int cc=0;cc<8;cc++){
      int gp = cg*8 + cc;
      sv[cc] = g5[gp]*srs; bvv[cc] = b5[gp];
    }
#pragma unroll
    for (int rr=0;rr<4;rr++){
      size_t row = r0 + rg*4 + rr;
      float* yr = h5 + row*128 + cg*8;
#pragma unroll
      for (int c4=0;c4<2;c4++){
        float y0 = sv[c4*4+0]*acc[rr][c4*4+0] + bvv[c4*4+0];
        float y1 = sv[c4*4+1]*acc[rr][c4*4+1] + bvv[c4*4+1];
        float y2 = sv[c4*4+2]*acc[rr][c4*4+2] + bvv[c4*4+2];
        float y3 = sv[c4*4+3]*acc[rr][c4*4+3] + bvv[c4*4+3];
        *(float4*)&yr[c4*4] = make_float4(mishf(y0),mishf(y1),mishf(y2),mishf(y3));
      }
    }
  }
}

// ---------------- fused MLP W6..W9: h5 -> h6(LDS) -> h7(LDS) -> h8(regs) -> out
__global__ __launch_bounds__(256) void k_mlp69(
    const float* __restrict__ h5g, const float* __restrict__ x2g, const float* __restrict__ x1g,
    const float* __restrict__ W6, const float* __restrict__ g6, const float* __restrict__ b6,
    const float* __restrict__ W7, const float* __restrict__ g7, const float* __restrict__ b7,
    const float* __restrict__ W8, const float* __restrict__ g8, const float* __restrict__ b8,
    const float* __restrict__ W9, float* __restrict__ out)
{
  __shared__ float Xt[32*68];
  __shared__ float Wt[32*68];
  __shared__ float h6t[64*68];     // row-major [row][col], stride 68
  __shared__ float h7t[64*68];
  __shared__ float w9s[128];
  const int t  = threadIdx.x;
  const int r0 = blockIdx.x*64;
  const int cg = t & 15, rg = t >> 4;
  const float srs = rsqrtf(1.f + 1e-5f);
  if (t < 128) w9s[t] = W9[t];

  float acc8[4][4];     // stage C result (W8), kept in regs

  // ---- stage A: W6 (C=128 from h5 global), P=64 -> h6t ----
  {
    float acc[4][4];
#pragma unroll
    for (int a=0;a<4;a++)
#pragma unroll
      for (int c=0;c<4;c++) acc[a][c]=0.f;
    for (int kt = 0; kt < 4; ++kt){
      const int k0 = kt*32;
#pragma unroll
      for (int e = t; e < 64*32; e += 256){
        int kk = e & 31, r = e >> 5;
        Xt[kk*68 + r] = h5g[(size_t)(r0+r)*128 + k0 + kk];
      }
#pragma unroll
      for (int e = t; e < 64*32; e += 256){
        int kk = e & 31, p = e >> 5;
        Wt[kk*68 + p] = W6[(size_t)p*128 + k0 + kk];
      }
      __syncthreads();
#pragma unroll
      for (int kk=0;kk<32;kk++){
        float4 xv = *(const float4*)&Xt[kk*68 + rg*4];
        float xr[4] = {xv.x, xv.y, xv.z, xv.w};
        float4 w4v = *(const float4*)&Wt[kk*68 + cg*4];
        float wv[4] = {w4v.x, w4v.y, w4v.z, w4v.w};
#pragma unroll
        for (int rr=0;rr<4;rr++)
#pragma unroll
          for (int cc=0;cc<4;cc++)
            acc[rr][cc] = fmaf(xr[rr], wv[cc], acc[rr][cc]);
      }
      __syncthreads();
    }
#pragma unroll
    for (int cc=0;cc<4;cc++){
      int gp = cg*4 + cc;
      float sv = g6[gp]*srs, bv = b6[gp];
#pragma unroll
      for (int rr=0;rr<4;rr++){
        float y = sv*acc[rr][cc] + bv;
        h6t[(rg*4+rr)*68 + gp] = mishf(y);
      }
    }
  }
  __syncthreads();

  // ---- stage B: W7 (C=128 = cat(h6 LDS, x2 global)), P=64 -> h7t ----
  {
    float acc[4][4];
#pragma unroll
    for (int a=0;a<4;a++)
#pragma unroll
      for (int c=0;c<4;c++) acc[a][c]=0.f;
    for (int kt = 0; kt < 4; ++kt){
      const int k0 = kt*32;
#pragma unroll
      for (int e = t; e < 64*32; e += 256){
        int kk = e & 31, r = e >> 5;
        int gk = k0 + kk;
        float v = (gk < 64) ? h6t[r*68 + gk]
                            : x2g[(size_t)(r0+r)*64 + (gk - 64)];
        Xt[kk*68 + r] = v;
      }
#pragma unroll
      for (int e = t; e < 64*32; e += 256){
        int kk = e & 31, p = e >> 5;
        Wt[kk*68 + p] = W7[(size_t)p*128 + k0 + kk];
      }
      __syncthreads();
#pragma unroll
      for (int kk=0;kk<32;kk++){
        float4 xv = *(const float4*)&Xt[kk*68 + rg*4];
        float xr[4] = {xv.x, xv.y, xv.z, xv.w};
        float4 w4v = *(const float4*)&Wt[kk*68 + cg*4];
        float wv[4] = {w4v.x, w4v.y, w4v.z, w4v.w};
#pragma unroll
        for (int rr=0;rr<4;rr++)
#pragma unroll
          for (int cc=0;cc<4;cc++)
            acc[rr][cc] = fmaf(xr[rr], wv[cc], acc[rr][cc]);
      }
      __syncthreads();
    }
#pragma unroll
    for (int cc=0;cc<4;cc++){
      int gp = cg*4 + cc;
      float sv = g7[gp]*srs, bv = b7[gp];
#pragma unroll
      for (int rr=0;rr<4;rr++){
        float y = sv*acc[rr][cc] + bv;
        h7t[(rg*4+rr)*68 + gp] = mishf(y);
      }
    }
  }
  __syncthreads();

  // ---- stage C: W8 (C=128 = cat(h7 LDS, x1 global)), P=64 -> acc8 regs ----
  {
#pragma unroll
    for (int a=0;a<4;a++)
#pragma unroll
      for (int c=0;c<4;c++) acc8[a][c]=0.f;
    for (int kt = 0; kt < 4; ++kt){
      const int k0 = kt*32;
#pragma unroll
      for (int e = t; e < 64*32; e += 256){
        int kk = e & 31, r = e >> 5;
        int gk = k0 + kk;
        float v = (gk < 64) ? h7t[r*68 + gk]
                            : x1g[(size_t)(r0+r)*64 + (gk - 64)];
        Xt[kk*68 + r] = v;
      }
#pragma unroll
      for (int e = t; e < 64*32; e += 256){
        int kk = e & 31, p = e >> 5;
        Wt[kk*68 + p] = W8[(size_t)p*128 + k0 + kk];
      }
      __syncthreads();
#pragma unroll
      for (int kk=0;kk<32;kk++){
        float4 xv = *(const float4*)&Xt[kk*68 + rg*4];
        float xr[4] = {xv.x, xv.y, xv.z, xv.w};
        float4 w4v = *(const float4*)&Wt[kk*68 + cg*4];
        float wv[4] = {w4v.x, w4v.y, w4v.z, w4v.w};
#pragma unroll
        for (int rr=0;rr<4;rr++)
#pragma unroll
          for (int cc=0;cc<4;cc++)
            acc8[rr][cc] = fmaf(xr[rr], wv[cc], acc8[rr][cc]);
      }
      __syncthreads();
    }
  }

  // ---- stage D: BN+mish + W9 projection (shfl-reduce over 16 cg lanes) ----
  float s0[4] = {0.f,0.f,0.f,0.f}, s1[4] = {0.f,0.f,0.f,0.f};
#pragma unroll
  for (int cc=0;cc<4;cc++){
    int p = cg*4 + cc;
    float sv = g8[p]*srs, bv = b8[p];
    float w90 = w9s[p], w91 = w9s[64+p];
#pragma unroll
    for (int rr=0;rr<4;rr++){
      float y = mishf(fmaf(sv, acc8[rr][cc], bv));
      s0[rr] = fmaf(w90, y, s0[rr]);
      s1[rr] = fmaf(w91, y, s1[rr]);
    }
  }
#pragma unroll
  for (int rr=0;rr<4;rr++){
    float v0 = s0[rr], v1 = s1[rr];
#pragma unroll
    for (int m=1;m<16;m<<=1){
      v0 += __shfl_xor(v0, m);
      v1 += __shfl_xor(v1, m);
    }
    if (cg == 0){
      int row = r0 + rg*4 + rr;
      int b = row >> 12, i = row & (N_-1);
      out[((size_t)b*2 + 0)*N_ + i] = v0;
      out[((size_t)b*2 + 1)*N_ + i] = v1;
    }
  }
}

// ---------------- edge gather + BN + mish + max over k ----------------
template<int O>
__global__ __launch_bounds__(256) void k_edgemax(
    const float* __restrict__ ua, const int* __restrict__ idx,
    const float* __restrict__ g, const float* __restrict__ bb,
    float* __restrict__ Y)
{
  constexpr int TPR = O/4;
  const int gt = blockIdx.x*256 + threadIdx.x;
  const int m  = gt / TPR;
  const int og = gt % TPR;
  if (m >= M_) return;
  const int base = m & ~(N_-1);
  const int P = 2*O;
  const float4 u0 = *(const float4*)&ua[(size_t)m*P + og*4];
  const float4 a0 = *(const float4*)&ua[(size_t)m*P + O + og*4];
  const float srs = rsqrtf(1.f + 1e-5f);
  const float4 gv  = *(const float4*)&g[og*4];
  const float4 bv4 = *(const float4*)&bb[og*4];
  const float sx = gv.x*srs, sy = gv.y*srs, sz = gv.z*srs, sw = gv.w*srs;
  const float cx = a0.x - u0.x, cy = a0.y - u0.y, cz = a0.z - u0.z, cw = a0.w - u0.w;
  float mx = -INFINITY, my = -INFINITY, mz = -INFINITY, mw = -INFINITY;
  const int* id = idx + (size_t)m*KNN;
#pragma unroll
  for (int k=0;k<KNN;k++){
    int j = id[k];
    const float4 uj = *(const float4*)&ua[(size_t)(base + j)*P + og*4];
    float zx = fmaf(sx, uj.x + cx, bv4.x);
    float zy = fmaf(sy, uj.y + cy, bv4.y);
    float zz = fmaf(sz, uj.z + cz, bv4.z);
    float zw = fmaf(sw, uj.w + cw, bv4.w);
    mx = fmaxf(mx, mishf(zx));
    my = fmaxf(my, mishf(zy));
    mz = fmaxf(mz, mishf(zz));
    mw = fmaxf(mw, mishf(zw));
  }
  *(float4*)&Y[(size_t)m*O + og*4] = make_float4(mx,my,mz,mw);
}

extern "C" void kernel_launch(void* const* d_in, const int* in_sizes, int n_in,
                              void* d_out, int out_size, void* d_ws, size_t ws_size,
                              hipStream_t stream)
{
  const float* x  = (const float*)d_in[0];
  const float* W1 = (const float*)d_in[1];
  const float* W2 = (const float*)d_in[2];
  const float* W3 = (const float*)d_in[3];
  const float* W4 = (const float*)d_in[4];
  const float* W5 = (const float*)d_in[5];
  const float* W6 = (const float*)d_in[6];
  const float* W7 = (const float*)d_in[7];
  const float* W8 = (const float*)d_in[8];
  const float* W9 = (const float*)d_in[9];
  const float* g1 = (const float*)d_in[10]; const float* b1 = (const float*)d_in[11];
  const float* g2 = (const float*)d_in[12]; const float* b2 = (const float*)d_in[13];
  const float* g3 = (const float*)d_in[14]; const float* b3 = (const float*)d_in[15];
  const float* g4 = (const float*)d_in[16]; const float* b4 = (const float*)d_in[17];
  const float* g5 = (const float*)d_in[18]; const float* b5 = (const float*)d_in[19];
  const float* g6 = (const float*)d_in[20]; const float* b6 = (const float*)d_in[21];
  const float* g7 = (const float*)d_in[22]; const float* b7 = (const float*)d_in[23];
  const float* g8 = (const float*)d_in[24]; const float* b8 = (const float*)d_in[25];
  float* out = (float*)d_out;

  float* ws  = (float*)d_ws;
  float* xp  = ws;                       // 98304
  float* xx  = xp + 98304;               // 32768
  float4* xp4 = (float4*)(xx + 32768);   // 131072 floats
  int*   idx = (int*)(xx + 32768 + 131072);  // 327680 ints
  float* ua  = (float*)(idx + 327680);   // 8388608 floats (max M*256)
  float* x1  = ua + 8388608;             // M*64
  float* x2  = x1 + 2097152;             // M*64
  float* x3  = x2 + 2097152;             // M*128
  float* h5  = x3 + 4194304;             // M*128
  // aliases into the (dead-during-kNN) ua region:
  ushort* Xhi = (ushort*)ua;             // M*64 ushorts
  ushort* Xlo = (ushort*)(ua + 1048576); // M*64 ushorts
  ull*    part = (ull*)(ua + 2097152);   // M*8*10 u64 (dead before gemm writes ua)

  const dim3 blk(256);
  const float* nullf = nullptr;

  // ---- stage 1 (C=3 -> 64) ----
  k_transpose_x<<<dim3(M_/256), blk, 0, stream>>>(x, xp, xp4);
  k_knn3s<<<dim3(1024), blk, 0, stream>>>(xp4, part);
  k_knnmerge8<<<dim3(M_/256), blk, 0, stream>>>(part, idx);
  k_gemm<128><<<dim3(M_/64, 1), blk, 0, stream>>>(xp, 3, nullf, 0,
      W1, 63, 6, 6, 3, nullf, nullf, 0, ua, 128);
  k_edgemax<64><<<dim3(M_*16/256), blk, 0, stream>>>(ua, idx, g1, b1, x1);

  // ---- stage 2 (64 -> 64) ----
  k_cvtxx<<<dim3(M_/256), blk, 0, stream>>>(x1, Xhi, Xlo, xx);
  k_knn64m<<<dim3(512), blk, 0, stream>>>(Xhi, Xlo, xx, idx);
  k_gemm<128><<<dim3(M_/64, 1), blk, 0, stream>>>(x1, 64, nullf, 0,
      W2, 63, 6, 128, 64, nullf, nullf, 0, ua, 128);
  k_edgemax<64><<<dim3(M_*16/256), blk, 0, stream>>>(ua, idx, g2, b2, x2);

  // ---- stage 3 (64 -> 128) ----
  k_cvtxx<<<dim3(M_/256), blk, 0, stream>>>(x2, Xhi, Xlo, xx);
  k_knn64m<<<dim3(512), blk, 0, stream>>>(Xhi, Xlo, xx, idx);
  k_gemm<128><<<dim3(M_/64, 2), blk, 0, stream>>>(x2, 64, nullf, 0,
      W3, 127, 7, 128, 64, nullf, nullf, 0, ua, 256);
  k_edgemax<128><<<dim3(M_*32/256), blk, 0, stream>>>(ua, idx, g3, b3, x3);

  // ---- MLP head (fused: 6 dispatches -> 2) ----
  k_mlp45<<<dim3(M_/64), blk, 0, stream>>>(x3, W4, g4, b4, W5, g5, b5, h5);
  k_mlp69<<<dim3(M_/64), blk, 0, stream>>>(h5, x2, x1,
      W6, g6, b6, W7, g7, b7, W8, g8, b8, W9, out);
}

// Round 19
// 1483.382 us; speedup vs baseline: 1.0007x; 1.0007x over previous
//
#include <hip/hip_runtime.h>
#include <hip/hip_bf16.h>
#include <math.h>
#include <float.h>

#define B_ 8
#define N_ 4096
#define M_ (B_*N_)
#define KNN 10

typedef unsigned long long ull;
typedef __attribute__((ext_vector_type(8))) short s16x8;
typedef __attribute__((ext_vector_type(4))) float f32x4;

__device__ __forceinline__ float mishf(float x){
  float sp = (x > 20.f) ? x : __logf(1.f + __expf(x));
  float e2 = __expf(-2.f*sp);
  float th = (1.f - e2) / (1.f + e2);
  return x * th;
}

__device__ __forceinline__ ull shfl_xor_u64(ull v, int mask){
  unsigned lo = (unsigned)v, hi = (unsigned)(v >> 32);
  lo = (unsigned)__shfl_xor((int)lo, mask);
  hi = (unsigned)__shfl_xor((int)hi, mask);
  return ((ull)hi << 32) | lo;
}
__device__ __forceinline__ ull shfl_u64(ull v, int src){
  unsigned lo = (unsigned)v, hi = (unsigned)(v >> 32);
  lo = (unsigned)__shfl((int)lo, src);
  hi = (unsigned)__shfl((int)hi, src);
  return ((ull)hi << 32) | lo;
}
__device__ __forceinline__ int mbcnt_lt(ull mask){
  return __builtin_amdgcn_mbcnt_hi((unsigned)(mask>>32),
         __builtin_amdgcn_mbcnt_lo((unsigned)mask, 0));
}
__device__ __forceinline__ unsigned mono_u32(float f){
  unsigned u = __float_as_uint(f);
  return u ^ ((unsigned)((int)u >> 31) | 0x80000000u);
}
__device__ __forceinline__ float unmono(unsigned vk){
  unsigned u = (vk & 0x80000000u) ? (vk ^ 0x80000000u) : ~vk;
  return __uint_as_float(u);
}
// async global->LDS, 16B per lane; lds dest is wave-uniform base + lane*16
__device__ __forceinline__ void gload_lds16(const void* g, void* l){
  __builtin_amdgcn_global_load_lds(
      (const __attribute__((address_space(1))) unsigned int*)g,
      (__attribute__((address_space(3))) unsigned int*)l, 16, 0, 0);
}

// ---------------- transpose x (B,3,N) -> xp (B*N,3) + xp4 {x,y,z,-xx/2} ------
__global__ __launch_bounds__(256) void k_transpose_x(const float* __restrict__ x,
                                                     float* __restrict__ xp,
                                                     float4* __restrict__ xp4){
  int n = blockIdx.x*256 + threadIdx.x;
  if (n >= M_) return;
  int b = n >> 12, i = n & (N_-1);
  const float* xb = x + (size_t)b*3*N_;
  float v0 = xb[i], v1 = xb[N_+i], v2 = xb[2*N_+i];
  float* o = xp + (size_t)n*3;
  o[0]=v0; o[1]=v1; o[2]=v2;
  float s = fmaf(v0,v0,0.f); s = fmaf(v1,v1,s); s = fmaf(v2,v2,s);
  xp4[n] = make_float4(v0, v1, v2, -0.5f*s);
}

// ---------------- fused: xx (exact k_xx<64> fmaf order) + bf16 hi/lo split ----
__global__ __launch_bounds__(256) void k_cvtxx(const float* __restrict__ X,
                                               ushort* __restrict__ Xhi,
                                               ushort* __restrict__ Xlo,
                                               float* __restrict__ xx){
  int n = blockIdx.x*256 + threadIdx.x;
  if (n >= M_) return;
  const float* r = X + (size_t)n*64;
  ushort* oh = Xhi + (size_t)n*64;
  ushort* ol = Xlo + (size_t)n*64;
  float s = 0.f;
#pragma unroll
  for (int g=0; g<8; ++g){
    float4 v0 = *(const float4*)(r + g*8);
    float4 v1 = *(const float4*)(r + g*8 + 4);
    float vv[8] = {v0.x,v0.y,v0.z,v0.w,v1.x,v1.y,v1.z,v1.w};
    unsigned hw[8], lw[8];
#pragma unroll
    for (int e=0;e<8;e++){
      float v = vv[e];
      s = fmaf(v,v,s);                       // c ascending: identical to k_xx<64>
      __hip_bfloat16 hb = __float2bfloat16(v);
      float hf = __bfloat162float(hb);
      __hip_bfloat16 lb = __float2bfloat16(v-hf);
      hw[e] = *(ushort*)&hb; lw[e] = *(ushort*)&lb;
    }
    uint4 hp, lp;
    hp.x = hw[0]|(hw[1]<<16); hp.y = hw[2]|(hw[3]<<16);
    hp.z = hw[4]|(hw[5]<<16); hp.w = hw[6]|(hw[7]<<16);
    lp.x = lw[0]|(lw[1]<<16); lp.y = lw[2]|(lw[3]<<16);
    lp.z = lw[4]|(lw[5]<<16); lp.w = lw[6]|(lw[7]<<16);
    *(uint4*)(oh + g*8) = hp;
    *(uint4*)(ol + g*8) = lp;
  }
  xx[n] = s;
}

// ---------------- C=3 kNN: per-thread-row streaming scan, 8 j-pieces --------
__global__ __launch_bounds__(256) void k_knn3s(const float4* __restrict__ xp4,
                                               ull* __restrict__ part){
  const int bid   = blockIdx.x;          // 8 batches x 16 rowgroups x 8 pieces
  const int piece = bid & 7;
  const int rg    = (bid >> 3) & 15;
  const int b     = bid >> 7;
  const int t     = threadIdx.x;
  const int row   = rg*256 + t;
  const float4 xi = xp4[(size_t)b*N_ + row];
  const float4* xj = xp4 + (size_t)b*N_ + piece*512;
  const int jbase = piece*512;

  ull kq[KNN];
#pragma unroll
  for (int q=0;q<KNN;q++) kq[q] = 0x007FFFFF00000000ull;   // packed -inf sentinel
  float T = -INFINITY;

  for (int jc=0; jc<512; jc+=8){
    float4 c[8];
#pragma unroll
    for (int u=0;u<8;u++) c[u] = xj[jc+u];
#pragma unroll
    for (int u=0;u<8;u++){
      float a = fmaf(xi.x, c[u].x, 0.f);
      a = fmaf(xi.y, c[u].y, a);
      a = fmaf(xi.z, c[u].z, a);
      float v = a + c[u].w;
      if (v > T){
        unsigned jinv = 4095u - (unsigned)(jbase + jc + u);
        ull ck = ((ull)mono_u32(v)<<32) | jinv;
#pragma unroll
        for (int q=0;q<KNN;q++){
          ull hi = ck > kq[q] ? ck : kq[q];
          ull lo = ck > kq[q] ? kq[q] : ck;
          kq[q] = hi; ck = lo;
        }
        T = unmono((unsigned)(kq[KNN-1] >> 32));
      }
    }
  }

  ull* o = part + ((size_t)(b*N_ + row)*8 + piece)*KNN;
#pragma unroll
  for (int q=0;q<KNN;q++) o[q] = kq[q];
}

// ---------------- merge eight sorted-10 key lists per row -> idx ----------------
__global__ __launch_bounds__(256) void k_knnmerge8(const ull* __restrict__ part,
                                                   int* __restrict__ idxout){
  int row = blockIdx.x*256 + threadIdx.x;
  if (row >= M_) return;
  const ull* p = part + (size_t)row*8*KNN;
  unsigned P = 0;
  int* o = idxout + (size_t)row*KNN;
  for (int s=0;s<KNN;s++){
    ull best = 0; int bl = 0;
#pragma unroll
    for (int l=0;l<8;l++){
      unsigned pl = (P >> (4*l)) & 15u;
      ull k = p[l*KNN + pl];
      if (k > best){ best = k; bl = l; }
    }
    P += 1u << (4*bl);
    o[s] = (int)(4095u - ((unsigned)best & 4095u));
  }
}

// ---------------- MFMA kNN (C=64, split-bf16 exact gram) -- R13 config -------
// Occupancy ladder FULLY explored (R7-R16): any min-waves>=3 cap spills;
// smaller LDS / 512-thr blocks don't raise residency. 385us = structural floor.
__global__ __launch_bounds__(256,2) void k_knn64m(const ushort* __restrict__ Xhi,
                                                  const ushort* __restrict__ Xlo,
                                                  const float* __restrict__ xx,
                                                  int* __restrict__ idxout){
  constexpr int JT  = 128;
  constexpr int NT  = N_/JT;
  constexpr int CAP = 320;
  __shared__ ushort XJhi[2][JT*64];   // content: LDS[r][c] = src[r][c ^ (r&7)] (16B chunks)
  __shared__ ushort XJlo[2][JT*64];
  __shared__ float  halfxx[2][JT];
  __shared__ ull    buf[4][CAP];

  const int t    = threadIdx.x;
  const int w    = t >> 6;
  const int lane = t & 63;
  const int b    = blockIdx.x & 7;          // XCD-swizzle: batch per XCD
  const int i0   = (blockIdx.x >> 3) * 64;
  const size_t rowbase = (size_t)b*N_;
  const float* xxb = xx + rowbase;

  const int arow = i0 + w*16 + (lane & 15);
  const ushort* Ah = Xhi + (rowbase + arow)*64;
  const ushort* Al = Xlo + (rowbase + arow)*64;
  const int ko = (lane >> 4)*8;
  s16x8 aH0 = *(const s16x8*)(Ah + ko);
  s16x8 aH1 = *(const s16x8*)(Ah + 32 + ko);
  s16x8 aL0 = *(const s16x8*)(Al + ko);
  s16x8 aL1 = *(const s16x8*)(Al + 32 + ko);

  ull kq[KNN];
#pragma unroll
  for (int q=0;q<KNN;q++) kq[q]=0ull;
  float Treg = -INFINITY;

  const int lr = lane >> 3;
  const int sc = (lane & 7) ^ lr;

  {
#pragma unroll
    for (int seg=0; seg<4; ++seg){
      const int row0 = w*32 + seg*8;
      gload_lds16(Xhi + (rowbase + row0 + lr)*64 + sc*8, &XJhi[0][row0*64]);
      gload_lds16(Xlo + (rowbase + row0 + lr)*64 + sc*8, &XJlo[0][row0*64]);
    }
    if (t < JT) halfxx[0][t] = 0.5f*xxb[t];
  }
  __syncthreads();

  for (int jt = 0; jt < NT; ++jt){
    const int cur = jt & 1;
    const int j0 = jt*JT;

    float hnext = 0.f;
    if (jt < NT-1){
      const size_t nb0 = rowbase + j0 + JT;
#pragma unroll
      for (int seg=0; seg<4; ++seg){
        const int row0 = w*32 + seg*8;
        gload_lds16(Xhi + (nb0 + row0 + lr)*64 + sc*8, &XJhi[cur^1][row0*64]);
        gload_lds16(Xlo + (nb0 + row0 + lr)*64 + sc*8, &XJlo[cur^1][row0*64]);
      }
      if (t < JT) hnext = 0.5f*xxb[j0 + JT + t];
    }

    f32x4 acc[8];
#pragma unroll
    for (int cb=0;cb<8;cb++) acc[cb] = (f32x4){0.f,0.f,0.f,0.f};

#pragma unroll
    for (int cb=0;cb<8;cb++){
      const int brow = cb*16 + (lane & 15);
      const unsigned sw = ((unsigned)(brow & 7)) << 4;
      const char* ph = (const char*)&XJhi[cur][0] + brow*128;
      const char* pl = (const char*)&XJlo[cur][0] + brow*128;
      const int kb0 = (int)((unsigned)((lane>>4)<<4) ^ sw);
      const int kb1 = (int)((unsigned)(64 | ((lane>>4)<<4)) ^ sw);
      s16x8 bh0 = *(const s16x8*)(ph + kb0);
      s16x8 bl0 = *(const s16x8*)(pl + kb0);
      s16x8 bh1 = *(const s16x8*)(ph + kb1);
      s16x8 bl1 = *(const s16x8*)(pl + kb1);
      f32x4 a = acc[cb];
      a = __builtin_amdgcn_mfma_f32_16x16x32_bf16(aH0, bh0, a, 0,0,0);
      a = __builtin_amdgcn_mfma_f32_16x16x32_bf16(aH0, bl0, a, 0,0,0);
      a = __builtin_amdgcn_mfma_f32_16x16x32_bf16(aL0, bh0, a, 0,0,0);
      a = __builtin_amdgcn_mfma_f32_16x16x32_bf16(aL0, bl0, a, 0,0,0);
      a = __builtin_amdgcn_mfma_f32_16x16x32_bf16(aH1, bh1, a, 0,0,0);
      a = __builtin_amdgcn_mfma_f32_16x16x32_bf16(aH1, bl1, a, 0,0,0);
      a = __builtin_amdgcn_mfma_f32_16x16x32_bf16(aL1, bh1, a, 0,0,0);
      a = __builtin_amdgcn_mfma_f32_16x16x32_bf16(aL1, bl1, a, 0,0,0);
      acc[cb] = a;
    }

    float hx[8];
#pragma unroll
    for (int cb=0;cb<8;cb++) hx[cb] = halfxx[cur][cb*16 + (lane & 15)];

    if (jt < NT-1 && t < JT) halfxx[cur^1][t] = hnext;

    if (jt == 0){
#pragma unroll
      for (int reg=0;reg<4;reg++){
        const unsigned rl = (unsigned)((lane>>4)*4 + reg);
        ull k8[8];
#pragma unroll
        for (int cb=0;cb<8;cb++){
          float v = acc[cb][reg] - hx[cb];
          unsigned jinv = 4095u - (unsigned)(cb*16 + (lane & 15));
          k8[cb] = ((ull)mono_u32(v)<<32) | ((ull)jinv<<4) | rl;
        }
#pragma unroll
        for (int q=0;q<KNN;q++){
          ull m = k8[0];
#pragma unroll
          for (int s=1;s<8;s++) m = m > k8[s] ? m : k8[s];
          ull v1 = shfl_xor_u64(m,1); m = m>v1?m:v1;
          ull v2 = shfl_xor_u64(m,2); m = m>v2?m:v2;
          ull v4 = shfl_xor_u64(m,4); m = m>v4?m:v4;
          ull v8 = shfl_xor_u64(m,8); m = m>v8?m:v8;
          ull mv = shfl_u64(m, (lane>>2)<<4);
          if (lane < 16 && (lane&3)==reg) kq[q] = mv;
#pragma unroll
          for (int s=0;s<8;s++) k8[s] = (k8[s]==m) ? 0ull : k8[s];
        }
      }
      Treg = unmono((unsigned)(kq[KNN-1] >> 32));
    } else {
      float Tf[4];
#pragma unroll
      for (int reg=0;reg<4;reg++) Tf[reg] = __shfl(Treg, (lane>>4)*4 + reg);
      int cnt = 0;
#pragma unroll
      for (int cb=0;cb<8;cb++){
#pragma unroll
        for (int reg=0;reg<4;reg++){
          float v = acc[cb][reg] - hx[cb];
          bool pass = v >= Tf[reg];
          ull mask = __ballot(pass);
          if (mask){
            if (pass){
              int slot = cnt + mbcnt_lt(mask);
              unsigned jinv = 4095u - (unsigned)(j0 + cb*16 + (lane & 15));
              ull key = ((ull)mono_u32(v)<<32) | ((ull)jinv<<4)
                        | (unsigned)((lane>>4)*4 + reg);
              if (slot < CAP) buf[w][slot] = key;
            }
            cnt += __popcll(mask);
          }
        }
      }
      if (cnt){
        int nb = cnt < CAP ? cnt : CAP;
        int pad = (4 - (nb & 3)) & 3;
        if (lane < pad && nb + lane < CAP) buf[w][nb + lane] = 0ull;
        int nb4 = nb + pad; if (nb4 > CAP) nb4 = CAP;
        for (int e=0;e<nb4;e+=4){
          ull c0=buf[w][e+0], c1=buf[w][e+1], c2=buf[w][e+2], c3=buf[w][e+3];
#pragma unroll
          for (int u=0;u<4;u++){
            ull k64 = (u==0)?c0:(u==1)?c1:(u==2)?c2:c3;
            if ((int)(k64 & 15ull) == lane && k64 > kq[KNN-1]){
              ull ck = k64;
#pragma unroll
              for (int q=0;q<KNN;q++){
                ull hi = ck > kq[q] ? ck : kq[q];
                ull lo = ck > kq[q] ? kq[q] : ck;
                kq[q] = hi; ck = lo;
              }
            }
          }
        }
        Treg = unmono((unsigned)(kq[KNN-1] >> 32));
      }
    }
    __syncthreads();
  }

  if (lane < 16){
    int* o = idxout + ((size_t)b*N_ + i0 + w*16 + lane)*KNN;
#pragma unroll
    for (int q=0;q<KNN;q++) o[q] = (int)(4095u - (unsigned)((kq[q]>>4) & 4095ull));
  }
}

// ---------------- generic GEMM: Y(M x Pfull) = act(s*(X1@Wa + X2@Wb)+b) ----------
template<int PT>
__global__ __launch_bounds__(256) void k_gemm(
    const float* __restrict__ X1, int C1,
    const float* __restrict__ X2, int C2,
    const float* __restrict__ W, int hmask, int hshift, int wstride, int hoff,
    const float* __restrict__ g, const float* __restrict__ bb, int act,
    float* __restrict__ Y, int Pfull)
{
  constexpr int CPT = PT/16;
  constexpr int WLS = PT + 4;
  __shared__ float Xt[32*68];
  __shared__ float Wt[32*WLS];
  const int t  = threadIdx.x;
  const int r0 = blockIdx.x*64;
  const int p0 = blockIdx.y*PT;
  const int cg = t & 15, rg = t >> 4;
  const int C = C1 + C2;
  const int nkt = (C + 31) >> 5;

  float acc[4][CPT];
#pragma unroll
  for (int a=0;a<4;a++)
#pragma unroll
    for (int c=0;c<CPT;c++) acc[a][c]=0.f;

  for (int kt = 0; kt < nkt; ++kt){
    const int k0 = kt*32;
#pragma unroll
    for (int e = t; e < 64*32; e += 256){
      int kk = e & 31, r = e >> 5;
      int gk = k0 + kk;
      float v = 0.f;
      if (gk < C1) v = X1[(size_t)(r0+r)*C1 + gk];
      else if (gk < C) v = X2[(size_t)(r0+r)*C2 + (gk - C1)];
      Xt[kk*68 + r] = v;
    }
#pragma unroll
    for (int e = t; e < PT*32; e += 256){
      int kk = e & 31, p = e >> 5;
      int gp = p0 + p;
      int wrow = (gp & hmask)*wstride + (gp >> hshift)*hoff;
      int gk = k0 + kk;
      Wt[kk*WLS + p] = (gk < C) ? W[(size_t)wrow + gk] : 0.f;
    }
    __syncthreads();
#pragma unroll
    for (int kk=0;kk<32;kk++){
      float4 xv = *(const float4*)&Xt[kk*68 + rg*4];
      float xr[4] = {xv.x, xv.y, xv.z, xv.w};
      float wv[CPT];
#pragma unroll
      for (int c4=0;c4<CPT/4;c4++){
        float4 w4 = *(const float4*)&Wt[kk*WLS + cg*CPT + c4*4];
        wv[c4*4+0]=w4.x; wv[c4*4+1]=w4.y; wv[c4*4+2]=w4.z; wv[c4*4+3]=w4.w;
      }
#pragma unroll
      for (int rr=0;rr<4;rr++)
#pragma unroll
        for (int cc=0;cc<CPT;cc++)
          acc[rr][cc] = fmaf(xr[rr], wv[cc], acc[rr][cc]);
    }
    __syncthreads();
  }

  const float srs = rsqrtf(1.f + 1e-5f);
  float sv[CPT], bvv[CPT];
#pragma unroll
  for (int cc=0;cc<CPT;cc++){
    int gp = p0 + cg*CPT + cc;
    if (g){ sv[cc] = g[gp]*srs; bvv[cc] = bb[gp]; } else { sv[cc]=1.f; bvv[cc]=0.f; }
  }
#pragma unroll
  for (int rr=0;rr<4;rr++){
    size_t row = r0 + rg*4 + rr;
    float* yr = Y + row*(size_t)Pfull + p0 + cg*CPT;
#pragma unroll
    for (int c4=0;c4<CPT/4;c4++){
      float y0 = sv[c4*4+0]*acc[rr][c4*4+0] + bvv[c4*4+0];
      float y1 = sv[c4*4+1]*acc[rr][c4*4+1] + bvv[c4*4+1];
      float y2 = sv[c4*4+2]*acc[rr][c4*4+2] + bvv[c4*4+2];
      float y3 = sv[c4*4+3]*acc[rr][c4*4+3] + bvv[c4*4+3];
      if (act){ y0=mishf(y0); y1=mishf(y1); y2=mishf(y2); y3=mishf(y3); }
      *(float4*)&yr[c4*4] = make_float4(y0,y1,y2,y3);
    }
  }
}

// ---------------- fused MLP W4+W5: x3 -> h4(LDS) -> cat(h4,x3) -> h5 ----------
__global__ __launch_bounds__(256) void k_mlp45(
    const float* __restrict__ x3g,
    const float* __restrict__ W4, const float* __restrict__ g4, const float* __restrict__ b4,
    const float* __restrict__ W5, const float* __restrict__ g5, const float* __restrict__ b5,
    float* __restrict__ h5)
{
  __shared__ float Xt[32*68];
  __shared__ float Wt[32*132];
  __shared__ float h4t[64*132];          // row-major [row][col], stride 132
  const int t  = threadIdx.x;
  const int r0 = blockIdx.x*64;
  const int cg = t & 15, rg = t >> 4;
  const float srs = rsqrtf(1.f + 1e-5f);

  // ---- stage A: W4 (C=128 from x3), P=128 ----
  {
    float acc[4][8];
#pragma unroll
    for (int a=0;a<4;a++)
#pragma unroll
      for (int c=0;c<8;c++) acc[a][c]=0.f;
    for (int kt = 0; kt < 4; ++kt){
      const int k0 = kt*32;
#pragma unroll
      for (int e = t; e < 64*32; e += 256){
        int kk = e & 31, r = e >> 5;
        Xt[kk*68 + r] = x3g[(size_t)(r0+r)*128 + k0 + kk];
      }
#pragma unroll
      for (int e = t; e < 128*32; e += 256){
        int kk = e & 31, p = e >> 5;
        Wt[kk*132 + p] = W4[(size_t)p*128 + k0 + kk];
      }
      __syncthreads();
#pragma unroll
      for (int kk=0;kk<32;kk++){
        float4 xv = *(const float4*)&Xt[kk*68 + rg*4];
        float xr[4] = {xv.x, xv.y, xv.z, xv.w};
        float wv[8];
#pragma unroll
        for (int c4=0;c4<2;c4++){
          float4 w4v = *(const float4*)&Wt[kk*132 + cg*8 + c4*4];
          wv[c4*4+0]=w4v.x; wv[c4*4+1]=w4v.y; wv[c4*4+2]=w4v.z; wv[c4*4+3]=w4v.w;
        }
#pragma unroll
        for (int rr=0;rr<4;rr++)
#pragma unroll
          for (int cc=0;cc<8;cc++)
            acc[rr][cc] = fmaf(xr[rr], wv[cc], acc[rr][cc]);
      }
      __syncthreads();
    }
    float sv[8], bvv[8];
#pragma unroll
    for (int cc=0;cc<8;cc++){
      int gp = cg*8 + cc;
      sv[cc] = g4[gp]*srs; bvv[cc] = b4[gp];
    }
#pragma unroll
    for (int rr=0;rr<4;rr++){
      int row = rg*4 + rr;
#pragma unroll
      for (int cc=0;cc<8;cc++){
        float y = sv[cc]*acc[rr][cc] + bvv[cc];
        h4t[row*132 + cg*8 + cc] = mishf(y);
      }
    }
  }
  __syncthreads();

  // ---- stage B: W5 (C=256 = cat(h4 LDS, x3 global)), P=128 ----
  {
    float acc[4][8];
#pragma unroll
    for (int a=0;a<4;a++)
#pragma unroll
      for (int c=0;c<8;c++) acc[a][c]=0.f;
    for (int kt = 0; kt < 8; ++kt){
      const int k0 = kt*32;
#pragma unroll
      for (int e = t; e < 64*32; e += 256){
        int kk = e & 31, r = e >> 5;
        int gk = k0 + kk;
        float v = (gk < 128) ? h4t[r*132 + gk]
                             : x3g[(size_t)(r0+r)*128 + (gk - 128)];
        Xt[kk*68 + r] = v;
      }
#pragma unroll
      for (int e = t; e < 128*32; e += 256){
        int kk = e & 31, p = e >> 5;
        Wt[kk*132 + p] = W5[(size_t)p*256 + k0 + kk];
      }
      __syncthreads();
#pragma unroll
      for (int kk=0;kk<32;kk++){
        float4 xv = *(const float4*)&Xt[kk*68 + rg*4];
        float xr[4] = {xv.x, xv.y, xv.z, xv.w};
        float wv[8];
#pragma unroll
        for (int c4=0;c4<2;c4++){
          float4 w4v = *(const float4*)&Wt[kk*132 + cg*8 + c4*4];
          wv[c4*4+0]=w4v.x; wv[c4*4+1]=w4v.y; wv[c4*4+2]=w4v.z; wv[c4*4+3]=w4v.w;
        }
#pragma unroll
        for (int rr=0;rr<4;rr++)
#pragma unroll
          for (int cc=0;cc<8;cc++)
            acc[rr][cc] = fmaf(xr[rr], wv[cc], acc[rr][cc]);
      }
      __syncthreads();
    }
    float sv[8], bvv[8];
#pragma unroll
    for (int cc=0;cc<8;cc++){
      int gp = cg*8 + cc;
      sv[cc] = g5[gp]*srs; bvv[cc] = b5[gp];
    }
#pragma unroll
    for (int rr=0;rr<4;rr++){
      size_t row = r0 + rg*4 + rr;
      float* yr = h5 + row*128 + cg*8;
#pragma unroll
      for (int c4=0;c4<2;c4++){
        float y0 = sv[c4*4+0]*acc[rr][c4*4+0] + bvv[c4*4+0];
        float y1 = sv[c4*4+1]*acc[rr][c4*4+1] + bvv[c4*4+1];
        float y2 = sv[c4*4+2]*acc[rr][c4*4+2] + bvv[c4*4+2];
        float y3 = sv[c4*4+3]*acc[rr][c4*4+3] + bvv[c4*4+3];
        *(float4*)&yr[c4*4] = make_float4(mishf(y0),mishf(y1),mishf(y2),mishf(y3));
      }
    }
  }
}

// ---------------- fused MLP W6..W9: h5 -> h6(LDS) -> h7(LDS) -> h8(regs) -> out
__global__ __launch_bounds__(256) void k_mlp69(
    const float* __restrict__ h5g, const float* __restrict__ x2g, const float* __restrict__ x1g,
    const float* __restrict__ W6, const float* __restrict__ g6, const float* __restrict__ b6,
    const float* __restrict__ W7, const float* __restrict__ g7, const float* __restrict__ b7,
    const float* __restrict__ W8, const float* __restrict__ g8, const float* __restrict__ b8,
    const float* __restrict__ W9, float* __restrict__ out)
{
  __shared__ float Xt[32*68];
  __shared__ float Wt[32*68];
  __shared__ float h6t[64*68];     // row-major [row][col], stride 68
  __shared__ float h7t[64*68];
  __shared__ float w9s[128];
  const int t  = threadIdx.x;
  const int r0 = blockIdx.x*64;
  const int cg = t & 15, rg = t >> 4;
  const float srs = rsqrtf(1.f + 1e-5f);
  if (t < 128) w9s[t] = W9[t];

  float acc8[4][4];     // stage C result (W8), kept in regs

  // ---- stage A: W6 (C=128 from h5 global), P=64 -> h6t ----
  {
    float acc[4][4];
#pragma unroll
    for (int a=0;a<4;a++)
#pragma unroll
      for (int c=0;c<4;c++) acc[a][c]=0.f;
    for (int kt = 0; kt < 4; ++kt){
      const int k0 = kt*32;
#pragma unroll
      for (int e = t; e < 64*32; e += 256){
        int kk = e & 31, r = e >> 5;
        Xt[kk*68 + r] = h5g[(size_t)(r0+r)*128 + k0 + kk];
      }
#pragma unroll
      for (int e = t; e < 64*32; e += 256){
        int kk = e & 31, p = e >> 5;
        Wt[kk*68 + p] = W6[(size_t)p*128 + k0 + kk];
      }
      __syncthreads();
#pragma unroll
      for (int kk=0;kk<32;kk++){
        float4 xv = *(const float4*)&Xt[kk*68 + rg*4];
        float xr[4] = {xv.x, xv.y, xv.z, xv.w};
        float4 w4v = *(const float4*)&Wt[kk*68 + cg*4];
        float wv[4] = {w4v.x, w4v.y, w4v.z, w4v.w};
#pragma unroll
        for (int rr=0;rr<4;rr++)
#pragma unroll
          for (int cc=0;cc<4;cc++)
            acc[rr][cc] = fmaf(xr[rr], wv[cc], acc[rr][cc]);
      }
      __syncthreads();
    }
#pragma unroll
    for (int cc=0;cc<4;cc++){
      int gp = cg*4 + cc;
      float sv = g6[gp]*srs, bv = b6[gp];
#pragma unroll
      for (int rr=0;rr<4;rr++){
        float y = sv*acc[rr][cc] + bv;
        h6t[(rg*4+rr)*68 + gp] = mishf(y);
      }
    }
  }
  __syncthreads();

  // ---- stage B: W7 (C=128 = cat(h6 LDS, x2 global)), P=64 -> h7t ----
  {
    float acc[4][4];
#pragma unroll
    for (int a=0;a<4;a++)
#pragma unroll
      for (int c=0;c<4;c++) acc[a][c]=0.f;
    for (int kt = 0; kt < 4; ++kt){
      const int k0 = kt*32;
#pragma unroll
      for (int e = t; e < 64*32; e += 256){
        int kk = e & 31, r = e >> 5;
        int gk = k0 + kk;
        float v = (gk < 64) ? h6t[r*68 + gk]
                            : x2g[(size_t)(r0+r)*64 + (gk - 64)];
        Xt[kk*68 + r] = v;
      }
#pragma unroll
      for (int e = t; e < 64*32; e += 256){
        int kk = e & 31, p = e >> 5;
        Wt[kk*68 + p] = W7[(size_t)p*128 + k0 + kk];
      }
      __syncthreads();
#pragma unroll
      for (int kk=0;kk<32;kk++){
        float4 xv = *(const float4*)&Xt[kk*68 + rg*4];
        float xr[4] = {xv.x, xv.y, xv.z, xv.w};
        float4 w4v = *(const float4*)&Wt[kk*68 + cg*4];
        float wv[4] = {w4v.x, w4v.y, w4v.z, w4v.w};
#pragma unroll
        for (int rr=0;rr<4;rr++)
#pragma unroll
          for (int cc=0;cc<4;cc++)
            acc[rr][cc] = fmaf(xr[rr], wv[cc], acc[rr][cc]);
      }
      __syncthreads();
    }
#pragma unroll
    for (int cc=0;cc<4;cc++){
      int gp = cg*4 + cc;
      float sv = g7[gp]*srs, bv = b7[gp];
#pragma unroll
      for (int rr=0;rr<4;rr++){
        float y = sv*acc[rr][cc] + bv;
        h7t[(rg*4+rr)*68 + gp] = mishf(y);
      }
    }
  }
  __syncthreads();

  // ---- stage C: W8 (C=128 = cat(h7 LDS, x1 global)), P=64 -> acc8 regs ----
  {
#pragma unroll
    for (int a=0;a<4;a++)
#pragma unroll
      for (int c=0;c<4;c++) acc8[a][c]=0.f;
    for (int kt = 0; kt < 4; ++kt){
      const int k0 = kt*32;
#pragma unroll
      for (int e = t; e < 64*32; e += 256){
        int kk = e & 31, r = e >> 5;
        int gk = k0 + kk;
        float v = (gk < 64) ? h7t[r*68 + gk]
                            : x1g[(size_t)(r0+r)*64 + (gk - 64)];
        Xt[kk*68 + r] = v;
      }
#pragma unroll
      for (int e = t; e < 64*32; e += 256){
        int kk = e & 31, p = e >> 5;
        Wt[kk*68 + p] = W8[(size_t)p*128 + k0 + kk];
      }
      __syncthreads();
#pragma unroll
      for (int kk=0;kk<32;kk++){
        float4 xv = *(const float4*)&Xt[kk*68 + rg*4];
        float xr[4] = {xv.x, xv.y, xv.z, xv.w};
        float4 w4v = *(const float4*)&Wt[kk*68 + cg*4];
        float wv[4] = {w4v.x, w4v.y, w4v.z, w4v.w};
#pragma unroll
        for (int rr=0;rr<4;rr++)
#pragma unroll
          for (int cc=0;cc<4;cc++)
            acc8[rr][cc] = fmaf(xr[rr], wv[cc], acc8[rr][cc]);
      }
      __syncthreads();
    }
  }

  // ---- stage D: BN+mish + W9 projection (shfl-reduce over 16 cg lanes) ----
  float s0[4] = {0.f,0.f,0.f,0.f}, s1[4] = {0.f,0.f,0.f,0.f};
#pragma unroll
  for (int cc=0;cc<4;cc++){
    int p = cg*4 + cc;
    float sv = g8[p]*srs, bv = b8[p];
    float w90 = w9s[p], w91 = w9s[64+p];
#pragma unroll
    for (int rr=0;rr<4;rr++){
      float y = mishf(fmaf(sv, acc8[rr][cc], bv));
      s0[rr] = fmaf(w90, y, s0[rr]);
      s1[rr] = fmaf(w91, y, s1[rr]);
    }
  }
#pragma unroll
  for (int rr=0;rr<4;rr++){
    float v0 = s0[rr], v1 = s1[rr];
#pragma unroll
    for (int m=1;m<16;m<<=1){
      v0 += __shfl_xor(v0, m);
      v1 += __shfl_xor(v1, m);
    }
    if (cg == 0){
      int row = r0 + rg*4 + rr;
      int b = row >> 12, i = row & (N_-1);
      out[((size_t)b*2 + 0)*N_ + i] = v0;
      out[((size_t)b*2 + 1)*N_ + i] = v1;
    }
  }
}

// ---------------- edge gather + BN + mish + max over k (XCD-batch-pinned) ----
// T1: batch = bid&7 -> round-robin XCD dispatch pins batch b to XCD b, so the
// random 10-neighbor gathers hit that XCD's L2 (batch ua: 2-4MB <= 4MB L2)
// instead of thrashing all 8 batches (16-32MB) through every L2.
template<int O>
__global__ __launch_bounds__(256) void k_edgemax(
    const float* __restrict__ ua, const int* __restrict__ idx,
    const float* __restrict__ g, const float* __restrict__ bb,
    float* __restrict__ Y)
{
  constexpr int TPR = O/4;
  const int b     = blockIdx.x & 7;
  const int inner = blockIdx.x >> 3;
  const int gt = inner*256 + threadIdx.x;
  const int mloc = gt / TPR;
  const int og = gt % TPR;
  if (mloc >= N_) return;
  const int m = b*N_ + mloc;
  const int base = b*N_;
  const int P = 2*O;
  const float4 u0 = *(const float4*)&ua[(size_t)m*P + og*4];
  const float4 a0 = *(const float4*)&ua[(size_t)m*P + O + og*4];
  const float srs = rsqrtf(1.f + 1e-5f);
  const float4 gv  = *(const float4*)&g[og*4];
  const float4 bv4 = *(const float4*)&bb[og*4];
  const float sx = gv.x*srs, sy = gv.y*srs, sz = gv.z*srs, sw = gv.w*srs;
  const float cx = a0.x - u0.x, cy = a0.y - u0.y, cz = a0.z - u0.z, cw = a0.w - u0.w;
  float mx = -INFINITY, my = -INFINITY, mz = -INFINITY, mw = -INFINITY;
  const int* id = idx + (size_t)m*KNN;
#pragma unroll
  for (int k=0;k<KNN;k++){
    int j = id[k];
    const float4 uj = *(const float4*)&ua[(size_t)(base + j)*P + og*4];
    float zx = fmaf(sx, uj.x + cx, bv4.x);
    float zy = fmaf(sy, uj.y + cy, bv4.y);
    float zz = fmaf(sz, uj.z + cz, bv4.z);
    float zw = fmaf(sw, uj.w + cw, bv4.w);
    mx = fmaxf(mx, mishf(zx));
    my = fmaxf(my, mishf(zy));
    mz = fmaxf(mz, mishf(zz));
    mw = fmaxf(mw, mishf(zw));
  }
  *(float4*)&Y[(size_t)m*O + og*4] = make_float4(mx,my,mz,mw);
}

extern "C" void kernel_launch(void* const* d_in, const int* in_sizes, int n_in,
                              void* d_out, int out_size, void* d_ws, size_t ws_size,
                              hipStream_t stream)
{
  const float* x  = (const float*)d_in[0];
  const float* W1 = (const float*)d_in[1];
  const float* W2 = (const float*)d_in[2];
  const float* W3 = (const float*)d_in[3];
  const float* W4 = (const float*)d_in[4];
  const float* W5 = (const float*)d_in[5];
  const float* W6 = (const float*)d_in[6];
  const float* W7 = (const float*)d_in[7];
  const float* W8 = (const float*)d_in[8];
  const float* W9 = (const float*)d_in[9];
  const float* g1 = (const float*)d_in[10]; const float* b1 = (const float*)d_in[11];
  const float* g2 = (const float*)d_in[12]; const float* b2 = (const float*)d_in[13];
  const float* g3 = (const float*)d_in[14]; const float* b3 = (const float*)d_in[15];
  const float* g4 = (const float*)d_in[16]; const float* b4 = (const float*)d_in[17];
  const float* g5 = (const float*)d_in[18]; const float* b5 = (const float*)d_in[19];
  const float* g6 = (const float*)d_in[20]; const float* b6 = (const float*)d_in[21];
  const float* g7 = (const float*)d_in[22]; const float* b7 = (const float*)d_in[23];
  const float* g8 = (const float*)d_in[24]; const float* b8 = (const float*)d_in[25];
  float* out = (float*)d_out;

  float* ws  = (float*)d_ws;
  float* xp  = ws;                       // 98304
  float* xx  = xp + 98304;               // 32768
  float4* xp4 = (float4*)(xx + 32768);   // 131072 floats
  int*   idx = (int*)(xx + 32768 + 131072);  // 327680 ints
  float* ua  = (float*)(idx + 327680);   // 8388608 floats (max M*256)
  float* x1  = ua + 8388608;             // M*64
  float* x2  = x1 + 2097152;             // M*64
  float* x3  = x2 + 2097152;             // M*128
  float* h5  = x3 + 4194304;             // M*128
  // aliases into the (dead-during-kNN) ua region:
  ushort* Xhi = (ushort*)ua;             // M*64 ushorts
  ushort* Xlo = (ushort*)(ua + 1048576); // M*64 ushorts
  ull*    part = (ull*)(ua + 2097152);   // M*8*10 u64 (dead before gemm writes ua)

  const dim3 blk(256);
  const float* nullf = nullptr;

  // ---- stage 1 (C=3 -> 64) ----
  k_transpose_x<<<dim3(M_/256), blk, 0, stream>>>(x, xp, xp4);
  k_knn3s<<<dim3(1024), blk, 0, stream>>>(xp4, part);
  k_knnmerge8<<<dim3(M_/256), blk, 0, stream>>>(part, idx);
  k_gemm<128><<<dim3(M_/64, 1), blk, 0, stream>>>(xp, 3, nullf, 0,
      W1, 63, 6, 6, 3, nullf, nullf, 0, ua, 128);
  k_edgemax<64><<<dim3(M_*16/256), blk, 0, stream>>>(ua, idx, g1, b1, x1);

  // ---- stage 2 (64 -> 64) ----
  k_cvtxx<<<dim3(M_/256), blk, 0, stream>>>(x1, Xhi, Xlo, xx);
  k_knn64m<<<dim3(512), blk, 0, stream>>>(Xhi, Xlo, xx, idx);
  k_gemm<128><<<dim3(M_/64, 1), blk, 0, stream>>>(x1, 64, nullf, 0,
      W2, 63, 6, 128, 64, nullf, nullf, 0, ua, 128);
  k_edgemax<64><<<dim3(M_*16/256), blk, 0, stream>>>(ua, idx, g2, b2, x2);

  // ---- stage 3 (64 -> 128) ----
  k_cvtxx<<<dim3(M_/256), blk, 0, stream>>>(x2, Xhi, Xlo, xx);
  k_knn64m<<<dim3(512), blk, 0, stream>>>(Xhi, Xlo, xx, idx);
  k_gemm<128><<<dim3(M_/64, 2), blk, 0, stream>>>(x2, 64, nullf, 0,
      W3, 127, 7, 128, 64, nullf, nullf, 0, ua, 256);
  k_edgemax<128><<<dim3(M_*32/256), blk, 0, stream>>>(ua, idx, g3, b3, x3);

  // ---- MLP head (fused) ----
  k_mlp45<<<dim3(M_/64), blk, 0, stream>>>(x3, W4, g4, b4, W5, g5, b5, h5);
  k_mlp69<<<dim3(M_/64), blk, 0, stream>>>(h5, x2, x1,
      W6, g6, b6, W7, g7, b7, W8, g8, b8, W9, out);
}

// Round 20
// 1446.392 us; speedup vs baseline: 1.0263x; 1.0256x over previous
//
#include <hip/hip_runtime.h>
#include <hip/hip_bf16.h>
#include <math.h>
#include <float.h>

#define B_ 8
#define N_ 4096
#define M_ (B_*N_)
#define KNN 10

typedef unsigned long long ull;
typedef __attribute__((ext_vector_type(8))) short s16x8;
typedef __attribute__((ext_vector_type(4))) float f32x4;

__device__ __forceinline__ float mishf(float x){
  float sp = (x > 20.f) ? x : __logf(1.f + __expf(x));
  float e2 = __expf(-2.f*sp);
  float th = (1.f - e2) / (1.f + e2);
  return x * th;
}

__device__ __forceinline__ ull shfl_xor_u64(ull v, int mask){
  unsigned lo = (unsigned)v, hi = (unsigned)(v >> 32);
  lo = (unsigned)__shfl_xor((int)lo, mask);
  hi = (unsigned)__shfl_xor((int)hi, mask);
  return ((ull)hi << 32) | lo;
}
__device__ __forceinline__ ull shfl_u64(ull v, int src){
  unsigned lo = (unsigned)v, hi = (unsigned)(v >> 32);
  lo = (unsigned)__shfl((int)lo, src);
  hi = (unsigned)__shfl((int)hi, src);
  return ((ull)hi << 32) | lo;
}
__device__ __forceinline__ int mbcnt_lt(ull mask){
  return __builtin_amdgcn_mbcnt_hi((unsigned)(mask>>32),
         __builtin_amdgcn_mbcnt_lo((unsigned)mask, 0));
}
__device__ __forceinline__ unsigned mono_u32(float f){
  unsigned u = __float_as_uint(f);
  return u ^ ((unsigned)((int)u >> 31) | 0x80000000u);
}
__device__ __forceinline__ float unmono(unsigned vk){
  unsigned u = (vk & 0x80000000u) ? (vk ^ 0x80000000u) : ~vk;
  return __uint_as_float(u);
}
// async global->LDS, 16B per lane; lds dest is wave-uniform base + lane*16
__device__ __forceinline__ void gload_lds16(const void* g, void* l){
  __builtin_amdgcn_global_load_lds(
      (const __attribute__((address_space(1))) unsigned int*)g,
      (__attribute__((address_space(3))) unsigned int*)l, 16, 0, 0);
}

// ---------------- transpose x (B,3,N) -> xp (B*N,3) + xp4 {x,y,z,-xx/2} ------
__global__ __launch_bounds__(256) void k_transpose_x(const float* __restrict__ x,
                                                     float* __restrict__ xp,
                                                     float4* __restrict__ xp4){
  int n = blockIdx.x*256 + threadIdx.x;
  if (n >= M_) return;
  int b = n >> 12, i = n & (N_-1);
  const float* xb = x + (size_t)b*3*N_;
  float v0 = xb[i], v1 = xb[N_+i], v2 = xb[2*N_+i];
  float* o = xp + (size_t)n*3;
  o[0]=v0; o[1]=v1; o[2]=v2;
  float s = fmaf(v0,v0,0.f); s = fmaf(v1,v1,s); s = fmaf(v2,v2,s);
  xp4[n] = make_float4(v0, v1, v2, -0.5f*s);
}

// ---------------- xx[n] = sum_c X[n,c]^2 (used by C=64 stages) ----------------
template<int C>
__global__ __launch_bounds__(256) void k_xx(const float* __restrict__ X,
                                            float* __restrict__ xx){
  int n = blockIdx.x*256 + threadIdx.x;
  if (n >= M_) return;
  const float* r = X + (size_t)n*C;
  float s = 0.f;
#pragma unroll
  for (int c=0;c<C;c++){ float v=r[c]; s = fmaf(v,v,s); }
  xx[n] = s;
}

// ---------------- split fp32 -> bf16 hi + bf16 lo (exact 2-term split) ------
__global__ __launch_bounds__(256) void k_cvt(const float* __restrict__ X,
                                             ushort* __restrict__ Xhi,
                                             ushort* __restrict__ Xlo){
  int i = blockIdx.x*256 + threadIdx.x;
  const float4* src = (const float4*)X + (size_t)i*2;
  float4 v0 = src[0], v1 = src[1];
  float vv[8] = {v0.x,v0.y,v0.z,v0.w,v1.x,v1.y,v1.z,v1.w};
  ushort h[8], l[8];
#pragma unroll
  for (int e=0;e<8;e++){
    __hip_bfloat16 hb = __float2bfloat16(vv[e]);
    float hf = __bfloat162float(hb);
    __hip_bfloat16 lb = __float2bfloat16(vv[e]-hf);
    h[e] = *(ushort*)&hb; l[e] = *(ushort*)&lb;
  }
  uint4 hp, lp;
  hp.x = (unsigned)h[0] | ((unsigned)h[1]<<16);
  hp.y = (unsigned)h[2] | ((unsigned)h[3]<<16);
  hp.z = (unsigned)h[4] | ((unsigned)h[5]<<16);
  hp.w = (unsigned)h[6] | ((unsigned)h[7]<<16);
  lp.x = (unsigned)l[0] | ((unsigned)l[1]<<16);
  lp.y = (unsigned)l[2] | ((unsigned)l[3]<<16);
  lp.z = (unsigned)l[4] | ((unsigned)l[5]<<16);
  lp.w = (unsigned)l[6] | ((unsigned)l[7]<<16);
  *(uint4*)(Xhi + (size_t)i*8) = hp;
  *(uint4*)(Xlo + (size_t)i*8) = lp;
}

// ---------------- C=3 kNN: per-thread-row streaming scan, 8 j-pieces --------
__global__ __launch_bounds__(256) void k_knn3s(const float4* __restrict__ xp4,
                                               ull* __restrict__ part){
  const int bid   = blockIdx.x;          // 8 batches x 16 rowgroups x 8 pieces
  const int piece = bid & 7;
  const int rg    = (bid >> 3) & 15;
  const int b     = bid >> 7;
  const int t     = threadIdx.x;
  const int row   = rg*256 + t;
  const float4 xi = xp4[(size_t)b*N_ + row];
  const float4* xj = xp4 + (size_t)b*N_ + piece*512;
  const int jbase = piece*512;

  ull kq[KNN];
#pragma unroll
  for (int q=0;q<KNN;q++) kq[q] = 0x007FFFFF00000000ull;   // packed -inf sentinel
  float T = -INFINITY;

  for (int jc=0; jc<512; jc+=8){
    float4 c[8];
#pragma unroll
    for (int u=0;u<8;u++) c[u] = xj[jc+u];
#pragma unroll
    for (int u=0;u<8;u++){
      float a = fmaf(xi.x, c[u].x, 0.f);
      a = fmaf(xi.y, c[u].y, a);
      a = fmaf(xi.z, c[u].z, a);
      float v = a + c[u].w;
      if (v > T){
        unsigned jinv = 4095u - (unsigned)(jbase + jc + u);
        ull ck = ((ull)mono_u32(v)<<32) | jinv;
#pragma unroll
        for (int q=0;q<KNN;q++){
          ull hi = ck > kq[q] ? ck : kq[q];
          ull lo = ck > kq[q] ? kq[q] : ck;
          kq[q] = hi; ck = lo;
        }
        T = unmono((unsigned)(kq[KNN-1] >> 32));
      }
    }
  }

  ull* o = part + ((size_t)(b*N_ + row)*8 + piece)*KNN;
#pragma unroll
  for (int q=0;q<KNN;q++) o[q] = kq[q];
}

// ---------------- merge eight sorted-10 key lists per row -> idx ----------------
__global__ __launch_bounds__(256) void k_knnmerge8(const ull* __restrict__ part,
                                                   int* __restrict__ idxout){
  int row = blockIdx.x*256 + threadIdx.x;
  if (row >= M_) return;
  const ull* p = part + (size_t)row*8*KNN;
  unsigned P = 0;
  int* o = idxout + (size_t)row*KNN;
  for (int s=0;s<KNN;s++){
    ull best = 0; int bl = 0;
#pragma unroll
    for (int l=0;l<8;l++){
      unsigned pl = (P >> (4*l)) & 15u;
      ull k = p[l*KNN + pl];
      if (k > best){ best = k; bl = l; }
    }
    P += 1u << (4*bl);
    o[s] = (int)(4095u - ((unsigned)best & 4095u));
  }
}

// ---------------- MFMA kNN (C=64, split-bf16 exact gram) -- best config ------
// Structural floor (R7-R16 ladder): 385us @ 8 waves/CU; all residency escapes
// spill or don't raise occupancy. Async gload_lds dbuf, one barrier/tile.
__global__ __launch_bounds__(256,2) void k_knn64m(const ushort* __restrict__ Xhi,
                                                  const ushort* __restrict__ Xlo,
                                                  const float* __restrict__ xx,
                                                  int* __restrict__ idxout){
  constexpr int JT  = 128;
  constexpr int NT  = N_/JT;
  constexpr int CAP = 320;
  __shared__ ushort XJhi[2][JT*64];   // content: LDS[r][c] = src[r][c ^ (r&7)] (16B chunks)
  __shared__ ushort XJlo[2][JT*64];
  __shared__ float  halfxx[2][JT];
  __shared__ ull    buf[4][CAP];

  const int t    = threadIdx.x;
  const int w    = t >> 6;
  const int lane = t & 63;
  const int b    = blockIdx.x & 7;          // XCD-swizzle: batch per XCD
  const int i0   = (blockIdx.x >> 3) * 64;
  const size_t rowbase = (size_t)b*N_;
  const float* xxb = xx + rowbase;

  const int arow = i0 + w*16 + (lane & 15);
  const ushort* Ah = Xhi + (rowbase + arow)*64;
  const ushort* Al = Xlo + (rowbase + arow)*64;
  const int ko = (lane >> 4)*8;
  s16x8 aH0 = *(const s16x8*)(Ah + ko);
  s16x8 aH1 = *(const s16x8*)(Ah + 32 + ko);
  s16x8 aL0 = *(const s16x8*)(Al + ko);
  s16x8 aL1 = *(const s16x8*)(Al + 32 + ko);

  ull kq[KNN];
#pragma unroll
  for (int q=0;q<KNN;q++) kq[q]=0ull;
  float Treg = -INFINITY;

  const int lr = lane >> 3;
  const int sc = (lane & 7) ^ lr;

  {
#pragma unroll
    for (int seg=0; seg<4; ++seg){
      const int row0 = w*32 + seg*8;
      gload_lds16(Xhi + (rowbase + row0 + lr)*64 + sc*8, &XJhi[0][row0*64]);
      gload_lds16(Xlo + (rowbase + row0 + lr)*64 + sc*8, &XJlo[0][row0*64]);
    }
    if (t < JT) halfxx[0][t] = 0.5f*xxb[t];
  }
  __syncthreads();

  for (int jt = 0; jt < NT; ++jt){
    const int cur = jt & 1;
    const int j0 = jt*JT;

    float hnext = 0.f;
    if (jt < NT-1){
      const size_t nb0 = rowbase + j0 + JT;
#pragma unroll
      for (int seg=0; seg<4; ++seg){
        const int row0 = w*32 + seg*8;
        gload_lds16(Xhi + (nb0 + row0 + lr)*64 + sc*8, &XJhi[cur^1][row0*64]);
        gload_lds16(Xlo + (nb0 + row0 + lr)*64 + sc*8, &XJlo[cur^1][row0*64]);
      }
      if (t < JT) hnext = 0.5f*xxb[j0 + JT + t];
    }

    f32x4 acc[8];
#pragma unroll
    for (int cb=0;cb<8;cb++) acc[cb] = (f32x4){0.f,0.f,0.f,0.f};

#pragma unroll
    for (int cb=0;cb<8;cb++){
      const int brow = cb*16 + (lane & 15);
      const unsigned sw = ((unsigned)(brow & 7)) << 4;
      const char* ph = (const char*)&XJhi[cur][0] + brow*128;
      const char* pl = (const char*)&XJlo[cur][0] + brow*128;
      const int kb0 = (int)((unsigned)((lane>>4)<<4) ^ sw);
      const int kb1 = (int)((unsigned)(64 | ((lane>>4)<<4)) ^ sw);
      s16x8 bh0 = *(const s16x8*)(ph + kb0);
      s16x8 bl0 = *(const s16x8*)(pl + kb0);
      s16x8 bh1 = *(const s16x8*)(ph + kb1);
      s16x8 bl1 = *(const s16x8*)(pl + kb1);
      f32x4 a = acc[cb];
      a = __builtin_amdgcn_mfma_f32_16x16x32_bf16(aH0, bh0, a, 0,0,0);
      a = __builtin_amdgcn_mfma_f32_16x16x32_bf16(aH0, bl0, a, 0,0,0);
      a = __builtin_amdgcn_mfma_f32_16x16x32_bf16(aL0, bh0, a, 0,0,0);
      a = __builtin_amdgcn_mfma_f32_16x16x32_bf16(aL0, bl0, a, 0,0,0);
      a = __builtin_amdgcn_mfma_f32_16x16x32_bf16(aH1, bh1, a, 0,0,0);
      a = __builtin_amdgcn_mfma_f32_16x16x32_bf16(aH1, bl1, a, 0,0,0);
      a = __builtin_amdgcn_mfma_f32_16x16x32_bf16(aL1, bh1, a, 0,0,0);
      a = __builtin_amdgcn_mfma_f32_16x16x32_bf16(aL1, bl1, a, 0,0,0);
      acc[cb] = a;
    }

    float hx[8];
#pragma unroll
    for (int cb=0;cb<8;cb++) hx[cb] = halfxx[cur][cb*16 + (lane & 15)];

    if (jt < NT-1 && t < JT) halfxx[cur^1][t] = hnext;

    if (jt == 0){
#pragma unroll
      for (int reg=0;reg<4;reg++){
        const unsigned rl = (unsigned)((lane>>4)*4 + reg);
        ull k8[8];
#pragma unroll
        for (int cb=0;cb<8;cb++){
          float v = acc[cb][reg] - hx[cb];
          unsigned jinv = 4095u - (unsigned)(cb*16 + (lane & 15));
          k8[cb] = ((ull)mono_u32(v)<<32) | ((ull)jinv<<4) | rl;
        }
#pragma unroll
        for (int q=0;q<KNN;q++){
          ull m = k8[0];
#pragma unroll
          for (int s=1;s<8;s++) m = m > k8[s] ? m : k8[s];
          ull v1 = shfl_xor_u64(m,1); m = m>v1?m:v1;
          ull v2 = shfl_xor_u64(m,2); m = m>v2?m:v2;
          ull v4 = shfl_xor_u64(m,4); m = m>v4?m:v4;
          ull v8 = shfl_xor_u64(m,8); m = m>v8?m:v8;
          ull mv = shfl_u64(m, (lane>>2)<<4);
          if (lane < 16 && (lane&3)==reg) kq[q] = mv;
#pragma unroll
          for (int s=0;s<8;s++) k8[s] = (k8[s]==m) ? 0ull : k8[s];
        }
      }
      Treg = unmono((unsigned)(kq[KNN-1] >> 32));
    } else {
      float Tf[4];
#pragma unroll
      for (int reg=0;reg<4;reg++) Tf[reg] = __shfl(Treg, (lane>>4)*4 + reg);
      int cnt = 0;
#pragma unroll
      for (int cb=0;cb<8;cb++){
#pragma unroll
        for (int reg=0;reg<4;reg++){
          float v = acc[cb][reg] - hx[cb];
          bool pass = v >= Tf[reg];
          ull mask = __ballot(pass);
          if (mask){
            if (pass){
              int slot = cnt + mbcnt_lt(mask);
              unsigned jinv = 4095u - (unsigned)(j0 + cb*16 + (lane & 15));
              ull key = ((ull)mono_u32(v)<<32) | ((ull)jinv<<4)
                        | (unsigned)((lane>>4)*4 + reg);
              if (slot < CAP) buf[w][slot] = key;
            }
            cnt += __popcll(mask);
          }
        }
      }
      if (cnt){
        int nb = cnt < CAP ? cnt : CAP;
        int pad = (4 - (nb & 3)) & 3;
        if (lane < pad && nb + lane < CAP) buf[w][nb + lane] = 0ull;
        int nb4 = nb + pad; if (nb4 > CAP) nb4 = CAP;
        for (int e=0;e<nb4;e+=4){
          ull c0=buf[w][e+0], c1=buf[w][e+1], c2=buf[w][e+2], c3=buf[w][e+3];
#pragma unroll
          for (int u=0;u<4;u++){
            ull k64 = (u==0)?c0:(u==1)?c1:(u==2)?c2:c3;
            if ((int)(k64 & 15ull) == lane && k64 > kq[KNN-1]){
              ull ck = k64;
#pragma unroll
              for (int q=0;q<KNN;q++){
                ull hi = ck > kq[q] ? ck : kq[q];
                ull lo = ck > kq[q] ? kq[q] : ck;
                kq[q] = hi; ck = lo;
              }
            }
          }
        }
        Treg = unmono((unsigned)(kq[KNN-1] >> 32));
      }
    }
    __syncthreads();
  }

  if (lane < 16){
    int* o = idxout + ((size_t)b*N_ + i0 + w*16 + lane)*KNN;
#pragma unroll
    for (int q=0;q<KNN;q++) o[q] = (int)(4095u - (unsigned)((kq[q]>>4) & 4095ull));
  }
}

// ---------------- generic GEMM: Y(M x Pfull) = act(s*(X1@Wa + X2@Wb)+b) ----------
template<int PT>
__global__ __launch_bounds__(256) void k_gemm(
    const float* __restrict__ X1, int C1,
    const float* __restrict__ X2, int C2,
    const float* __restrict__ W, int hmask, int hshift, int wstride, int hoff,
    const float* __restrict__ g, const float* __restrict__ bb, int act,
    float* __restrict__ Y, int Pfull)
{
  constexpr int CPT = PT/16;
  constexpr int WLS = PT + 4;
  __shared__ float Xt[32*68];
  __shared__ float Wt[32*WLS];
  const int t  = threadIdx.x;
  const int r0 = blockIdx.x*64;
  const int p0 = blockIdx.y*PT;
  const int cg = t & 15, rg = t >> 4;
  const int C = C1 + C2;
  const int nkt = (C + 31) >> 5;

  float acc[4][CPT];
#pragma unroll
  for (int a=0;a<4;a++)
#pragma unroll
    for (int c=0;c<CPT;c++) acc[a][c]=0.f;

  for (int kt = 0; kt < nkt; ++kt){
    const int k0 = kt*32;
#pragma unroll
    for (int e = t; e < 64*32; e += 256){
      int kk = e & 31, r = e >> 5;
      int gk = k0 + kk;
      float v = 0.f;
      if (gk < C1) v = X1[(size_t)(r0+r)*C1 + gk];
      else if (gk < C) v = X2[(size_t)(r0+r)*C2 + (gk - C1)];
      Xt[kk*68 + r] = v;
    }
#pragma unroll
    for (int e = t; e < PT*32; e += 256){
      int kk = e & 31, p = e >> 5;
      int gp = p0 + p;
      int wrow = (gp & hmask)*wstride + (gp >> hshift)*hoff;
      int gk = k0 + kk;
      Wt[kk*WLS + p] = (gk < C) ? W[(size_t)wrow + gk] : 0.f;
    }
    __syncthreads();
#pragma unroll
    for (int kk=0;kk<32;kk++){
      float4 xv = *(const float4*)&Xt[kk*68 + rg*4];
      float xr[4] = {xv.x, xv.y, xv.z, xv.w};
      float wv[CPT];
#pragma unroll
      for (int c4=0;c4<CPT/4;c4++){
        float4 w4 = *(const float4*)&Wt[kk*WLS + cg*CPT + c4*4];
        wv[c4*4+0]=w4.x; wv[c4*4+1]=w4.y; wv[c4*4+2]=w4.z; wv[c4*4+3]=w4.w;
      }
#pragma unroll
      for (int rr=0;rr<4;rr++)
#pragma unroll
        for (int cc=0;cc<CPT;cc++)
          acc[rr][cc] = fmaf(xr[rr], wv[cc], acc[rr][cc]);
    }
    __syncthreads();
  }

  const float srs = rsqrtf(1.f + 1e-5f);
  float sv[CPT], bvv[CPT];
#pragma unroll
  for (int cc=0;cc<CPT;cc++){
    int gp = p0 + cg*CPT + cc;
    if (g){ sv[cc] = g[gp]*srs; bvv[cc] = bb[gp]; } else { sv[cc]=1.f; bvv[cc]=0.f; }
  }
#pragma unroll
  for (int rr=0;rr<4;rr++){
    size_t row = r0 + rg*4 + rr;
    float* yr = Y + row*(size_t)Pfull + p0 + cg*CPT;
#pragma unroll
    for (int c4=0;c4<CPT/4;c4++){
      float y0 = sv[c4*4+0]*acc[rr][c4*4+0] + bvv[c4*4+0];
      float y1 = sv[c4*4+1]*acc[rr][c4*4+1] + bvv[c4*4+1];
      float y2 = sv[c4*4+2]*acc[rr][c4*4+2] + bvv[c4*4+2];
      float y3 = sv[c4*4+3]*acc[rr][c4*4+3] + bvv[c4*4+3];
      if (act){ y0=mishf(y0); y1=mishf(y1); y2=mishf(y2); y3=mishf(y3); }
      *(float4*)&yr[c4*4] = make_float4(y0,y1,y2,y3);
    }
  }
}

// ---------------- edge gather + BN + mish + max over k ----------------
template<int O>
__global__ __launch_bounds__(256) void k_edgemax(
    const float* __restrict__ ua, const int* __restrict__ idx,
    const float* __restrict__ g, const float* __restrict__ bb,
    float* __restrict__ Y)
{
  constexpr int TPR = O/4;
  const int gt = blockIdx.x*256 + threadIdx.x;
  const int m  = gt / TPR;
  const int og = gt % TPR;
  if (m >= M_) return;
  const int base = m & ~(N_-1);
  const int P = 2*O;
  const float4 u0 = *(const float4*)&ua[(size_t)m*P + og*4];
  const float4 a0 = *(const float4*)&ua[(size_t)m*P + O + og*4];
  const float srs = rsqrtf(1.f + 1e-5f);
  const float4 gv  = *(const float4*)&g[og*4];
  const float4 bv4 = *(const float4*)&bb[og*4];
  const float sx = gv.x*srs, sy = gv.y*srs, sz = gv.z*srs, sw = gv.w*srs;
  const float cx = a0.x - u0.x, cy = a0.y - u0.y, cz = a0.z - u0.z, cw = a0.w - u0.w;
  float mx = -INFINITY, my = -INFINITY, mz = -INFINITY, mw = -INFINITY;
  const int* id = idx + (size_t)m*KNN;
#pragma unroll
  for (int k=0;k<KNN;k++){
    int j = id[k];
    const float4 uj = *(const float4*)&ua[(size_t)(base + j)*P + og*4];
    float zx = fmaf(sx, uj.x + cx, bv4.x);
    float zy = fmaf(sy, uj.y + cy, bv4.y);
    float zz = fmaf(sz, uj.z + cz, bv4.z);
    float zw = fmaf(sw, uj.w + cw, bv4.w);
    mx = fmaxf(mx, mishf(zx));
    my = fmaxf(my, mishf(zy));
    mz = fmaxf(mz, mishf(zz));
    mw = fmaxf(mw, mishf(zw));
  }
  *(float4*)&Y[(size_t)m*O + og*4] = make_float4(mx,my,mz,mw);
}

// ---------------- final projection: out(B,2,N) = W9 @ h8 ----------------
__global__ __launch_bounds__(256) void k_final(const float* __restrict__ h,
                                               const float* __restrict__ W9,
                                               float* __restrict__ out){
  __shared__ float w[128];
  const int t = threadIdx.x;
  if (t < 128) w[t] = W9[t];
  __syncthreads();
  const int m = blockIdx.x*256 + t;
  if (m >= M_) return;
  const int b = m >> 12, i = m & (N_-1);
  const float* hr = h + (size_t)m*64;
  float s0 = 0.f, s1 = 0.f;
#pragma unroll
  for (int c=0;c<64;c++){ float v = hr[c]; s0 = fmaf(w[c], v, s0); s1 = fmaf(w[64+c], v, s1); }
  out[((size_t)b*2 + 0)*N_ + i] = s0;
  out[((size_t)b*2 + 1)*N_ + i] = s1;
}

extern "C" void kernel_launch(void* const* d_in, const int* in_sizes, int n_in,
                              void* d_out, int out_size, void* d_ws, size_t ws_size,
                              hipStream_t stream)
{
  const float* x  = (const float*)d_in[0];
  const float* W1 = (const float*)d_in[1];
  const float* W2 = (const float*)d_in[2];
  const float* W3 = (const float*)d_in[3];
  const float* W4 = (const float*)d_in[4];
  const float* W5 = (const float*)d_in[5];
  const float* W6 = (const float*)d_in[6];
  const float* W7 = (const float*)d_in[7];
  const float* W8 = (const float*)d_in[8];
  const float* W9 = (const float*)d_in[9];
  const float* g1 = (const float*)d_in[10]; const float* b1 = (const float*)d_in[11];
  const float* g2 = (const float*)d_in[12]; const float* b2 = (const float*)d_in[13];
  const float* g3 = (const float*)d_in[14]; const float* b3 = (const float*)d_in[15];
  const float* g4 = (const float*)d_in[16]; const float* b4 = (const float*)d_in[17];
  const float* g5 = (const float*)d_in[18]; const float* b5 = (const float*)d_in[19];
  const float* g6 = (const float*)d_in[20]; const float* b6 = (const float*)d_in[21];
  const float* g7 = (const float*)d_in[22]; const float* b7 = (const float*)d_in[23];
  const float* g8 = (const float*)d_in[24]; const float* b8 = (const float*)d_in[25];
  float* out = (float*)d_out;

  float* ws  = (float*)d_ws;
  float* xp  = ws;                       // 98304
  float* xx  = xp + 98304;               // 32768
  float4* xp4 = (float4*)(xx + 32768);   // 131072 floats
  int*   idx = (int*)(xx + 32768 + 131072);  // 327680 ints
  float* ua  = (float*)(idx + 327680);   // 8388608 floats (max M*256)
  float* x1  = ua + 8388608;             // M*64
  float* x2  = x1 + 2097152;             // M*64
  float* x3  = x2 + 2097152;             // M*128
  float* h4  = x3 + 4194304;             // M*128
  float* h5  = h4 + 4194304;             // M*128
  float* h6  = x3;
  float* h7  = h4;
  float* h8  = h5;
  // aliases into the (dead-during-kNN) ua region:
  ushort* Xhi = (ushort*)ua;             // M*64 ushorts
  ushort* Xlo = (ushort*)(ua + 1048576); // M*64 ushorts
  ull*    part = (ull*)(ua + 2097152);   // M*8*10 u64 (dead before gemm writes ua)

  const dim3 blk(256);
  const float* nullf = nullptr;

  // ---- stage 1 (C=3 -> 64) ----
  k_transpose_x<<<dim3(M_/256), blk, 0, stream>>>(x, xp, xp4);
  k_knn3s<<<dim3(1024), blk, 0, stream>>>(xp4, part);
  k_knnmerge8<<<dim3(M_/256), blk, 0, stream>>>(part, idx);
  k_gemm<128><<<dim3(M_/64, 1), blk, 0, stream>>>(xp, 3, nullf, 0,
      W1, 63, 6, 6, 3, nullf, nullf, 0, ua, 128);
  k_edgemax<64><<<dim3(M_*16/256), blk, 0, stream>>>(ua, idx, g1, b1, x1);

  // ---- stage 2 (64 -> 64) ----
  k_xx<64><<<dim3(M_/256), blk, 0, stream>>>(x1, xx);
  k_cvt<<<dim3(M_*64/(8*256)), blk, 0, stream>>>(x1, Xhi, Xlo);
  k_knn64m<<<dim3(512), blk, 0, stream>>>(Xhi, Xlo, xx, idx);
  k_gemm<128><<<dim3(M_/64, 1), blk, 0, stream>>>(x1, 64, nullf, 0,
      W2, 63, 6, 128, 64, nullf, nullf, 0, ua, 128);
  k_edgemax<64><<<dim3(M_*16/256), blk, 0, stream>>>(ua, idx, g2, b2, x2);

  // ---- stage 3 (64 -> 128) ----
  k_xx<64><<<dim3(M_/256), blk, 0, stream>>>(x2, xx);
  k_cvt<<<dim3(M_*64/(8*256)), blk, 0, stream>>>(x2, Xhi, Xlo);
  k_knn64m<<<dim3(512), blk, 0, stream>>>(Xhi, Xlo, xx, idx);
  k_gemm<128><<<dim3(M_/64, 2), blk, 0, stream>>>(x2, 64, nullf, 0,
      W3, 127, 7, 128, 64, nullf, nullf, 0, ua, 256);
  k_edgemax<128><<<dim3(M_*32/256), blk, 0, stream>>>(ua, idx, g3, b3, x3);

  // ---- MLP head ----
  k_gemm<128><<<dim3(M_/64, 1), blk, 0, stream>>>(x3, 128, nullf, 0,
      W4, 127, 7, 128, 0, g4, b4, 1, h4, 128);
  k_gemm<128><<<dim3(M_/64, 1), blk, 0, stream>>>(h4, 128, x3, 128,
      W5, 127, 7, 256, 0, g5, b5, 1, h5, 128);
  k_gemm<64><<<dim3(M_/64, 1), blk, 0, stream>>>(h5, 128, nullf, 0,
      W6, 63, 6, 128, 0, g6, b6, 1, h6, 64);
  k_gemm<64><<<dim3(M_/64, 1), blk, 0, stream>>>(h6, 64, x2, 64,
      W7, 63, 6, 128, 0, g7, b7, 1, h7, 64);
  k_gemm<64><<<dim3(M_/64, 1), blk, 0, stream>>>(h7, 64, x1, 64,
      W8, 63, 6, 128, 0, g8, b8, 1, h8, 64);
  k_final<<<dim3(M_/256), blk, 0, stream>>>(h8, W9, out);
}